// Round 5
// baseline (486.536 us; speedup 1.0000x reference)
//
#include <hip/hip_runtime.h>

// ---------------------------------------------------------------------------
// Types & helpers
// ---------------------------------------------------------------------------
typedef __attribute__((ext_vector_type(8))) short bf16x8;
typedef __attribute__((ext_vector_type(4))) float f32x4;

__device__ __forceinline__ short f2bf(float f) {
  union { float f; unsigned u; } a; a.f = f;
  unsigned r = a.u + 0x7fffu + ((a.u >> 16) & 1u);   // RNE
  return (short)(r >> 16);
}
__device__ __forceinline__ float bf2f(short s) {
  union { unsigned u; float f; } a;
  a.u = ((unsigned)(unsigned short)s) << 16; return a.f;
}
__device__ __forceinline__ float blo(unsigned u) { union { unsigned u; float f; } a; a.u = u << 16; return a.f; }
__device__ __forceinline__ float bhi(unsigned u) { union { unsigned u; float f; } a; a.u = u & 0xffff0000u; return a.f; }
__device__ __forceinline__ unsigned packbf(float lo, float hi) {
  return (unsigned)(unsigned short)f2bf(lo) | ((unsigned)(unsigned short)f2bf(hi) << 16);
}
__device__ __forceinline__ void ldscp16(const void* g, void* l) {
  __builtin_amdgcn_global_load_lds((const __attribute__((address_space(1))) void*)g,
                                   (__attribute__((address_space(3))) void*)l, 16, 0, 0);
}
__device__ __forceinline__ void stv(float* p, float v) { *p = v; }
__device__ __forceinline__ void stv(short* p, float v) { *p = f2bf(v); }

// ---------------------------------------------------------------------------
// Zero accumulators (ss_s | ss_t = 128 KB contiguous; ws is poisoned 0xAA)
// ---------------------------------------------------------------------------
__global__ __launch_bounds__(256) void zero_f(float* __restrict__ p) {
  p[blockIdx.x * 256 + threadIdx.x] = 0.f;
}

// ---------------------------------------------------------------------------
// Weight conversion to bf16, RMS gamma folded into the K dim of the
// attention projections: Wg[o][c] = W[o][c]*gamma[c].
// Order: qs,ks,vs(g_s) ps(none) qt,kt,vt(g_t) pt(none).
// ---------------------------------------------------------------------------
__global__ __launch_bounds__(256) void cvt_w(
    const float* __restrict__ w0, const float* __restrict__ w1,
    const float* __restrict__ w2, const float* __restrict__ w3,
    const float* __restrict__ w4, const float* __restrict__ w5,
    const float* __restrict__ w6, const float* __restrict__ w7,
    const float* __restrict__ g_s, const float* __restrict__ g_t,
    short* __restrict__ out) {
  int idx = blockIdx.x * 256 + threadIdx.x;          // 8 * 262144
  const float* ws[8] = {w0, w1, w2, w3, w4, w5, w6, w7};
  int wi = idx >> 18, c = idx & 511;
  float g = 1.f;
  if (wi <= 2) g = g_s[c];
  else if (wi >= 4 && wi <= 6) g = g_t[c];
  out[idx] = f2bf(ws[wi][idx & 262143] * g);
}

__global__ __launch_bounds__(256) void cvt_b(
    const float* __restrict__ b0, const float* __restrict__ b1,
    const float* __restrict__ b2, const float* __restrict__ b3,
    const float* __restrict__ b4, const float* __restrict__ b5,
    const float* __restrict__ b6, const float* __restrict__ b7,
    float* __restrict__ out) {
  int idx = blockIdx.x * 256 + threadIdx.x;          // 8 * 512
  const float* bs[8] = {b0, b1, b2, b3, b4, b5, b6, b7};
  out[idx] = bs[idx >> 9][idx & 511];
}

// ---------------------------------------------------------------------------
// Transpose + sum-of-squares. src: [512][16384] fp32 -> dst: [16384][512] bf16,
// ss[n] += sum_c src[c][n]^2. RMS factor applied later in GEMM epilogues.
// ---------------------------------------------------------------------------
__global__ __launch_bounds__(256) void txp_sumsq(
    const float* __restrict__ src, short* __restrict__ dst,
    float* __restrict__ ss) {
  constexpr long N = 16384;
  __shared__ short T[64][66];
  __shared__ float part[16][16][4];
  const int tid = threadIdx.x;
  const long n0 = (long)blockIdx.x * 64;
  const int c0 = blockIdx.y * 64;
  const int n4 = (tid & 15) * 4;
  float s0 = 0.f, s1 = 0.f, s2 = 0.f, s3 = 0.f;
#pragma unroll
  for (int i = 0; i < 4; ++i) {
    int cl = i * 16 + (tid >> 4);
    float4 v = *(const float4*)&src[(long)(c0 + cl) * N + n0 + n4];
    s0 += v.x * v.x; s1 += v.y * v.y; s2 += v.z * v.z; s3 += v.w * v.w;
    T[n4 + 0][cl] = f2bf(v.x); T[n4 + 1][cl] = f2bf(v.y);
    T[n4 + 2][cl] = f2bf(v.z); T[n4 + 3][cl] = f2bf(v.w);
  }
  part[tid >> 4][tid & 15][0] = s0; part[tid >> 4][tid & 15][1] = s1;
  part[tid >> 4][tid & 15][2] = s2; part[tid >> 4][tid & 15][3] = s3;
  __syncthreads();
  if (tid < 64) {
    float s = 0.f;
#pragma unroll
    for (int cg = 0; cg < 16; ++cg) s += part[cg][tid >> 2][tid & 3];
    atomicAdd(&ss[n0 + tid], s);
  }
#pragma unroll
  for (int p = 0; p < 4; ++p) {
    int nl = p * 16 + (tid >> 4);
    int cl = (tid & 15) * 4;
    uint2 o;
    o.x = (unsigned)(unsigned short)T[nl][cl] |
          ((unsigned)(unsigned short)T[nl][cl + 1] << 16);
    o.y = (unsigned)(unsigned short)T[nl][cl + 2] |
          ((unsigned)(unsigned short)T[nl][cl + 3] << 16);
    *(uint2*)&dst[(n0 + nl) * 512 + c0 + cl] = o;
  }
}

// ---------------------------------------------------------------------------
// Generic NT GEMM: D[i,j] = f( scale * sum_k A[i,k]*B[j,k] ) (+bias,+resid)
// SCALE_MODE: 0 none; 1 row-rms sqrt(512)/sqrt(ss[i]); 2 col-rms (ss[j])
// BIAS_MODE: 0 none, 1 row bias[i], 2 col bias[j].
// 128x128 tile, BK=64, 4 waves, mfma_f32_16x16x32_bf16, xor-swizzled LDS.
// ---------------------------------------------------------------------------
template <typename OutT, int BIAS_MODE, int SCALE_MODE, bool RESID>
__global__ __launch_bounds__(256, 3) void gemm_nt(
    const short* __restrict__ A, const short* __restrict__ B,
    OutT* __restrict__ D, const float* __restrict__ bias,
    const float* __restrict__ ssv, const float* __restrict__ resid,
    int K, int lda, int ldb, int ldd,
    long aBatch, long bBatch, long dBatch, float scale) {
  __shared__ short As[128 * 64];
  __shared__ short Bs[128 * 64];
  const int tid = threadIdx.x;
  const int bz = blockIdx.z;
  const long i0 = (long)blockIdx.x * 128;
  const long j0 = (long)blockIdx.y * 128;
  const short* Ab = A + bz * aBatch + i0 * lda;
  const short* Bb = B + bz * bBatch + j0 * ldb;
  const int srow = tid >> 3, scol = tid & 7;
  const int lane = tid & 63;
  const int wr = ((tid >> 7) & 1) * 64;
  const int wc = ((tid >> 6) & 1) * 64;
  const int quad = lane >> 4, l15 = lane & 15;

  f32x4 acc[4][4] = {};

  for (int k0 = 0; k0 < K; k0 += 64) {
    __syncthreads();
#pragma unroll
    for (int p = 0; p < 4; ++p) {
      int row = p * 32 + srow;
      int gc = (scol ^ (row & 7)) << 3;
      ldscp16(Ab + (long)row * lda + k0 + gc, &As[p * 2048 + tid * 8]);
    }
#pragma unroll
    for (int p = 0; p < 4; ++p) {
      int row = p * 32 + srow;
      int gc = (scol ^ (row & 7)) << 3;
      ldscp16(Bb + (long)row * ldb + k0 + gc, &Bs[p * 2048 + tid * 8]);
    }
    __syncthreads();
#pragma unroll
    for (int kk = 0; kk < 2; ++kk) {
      bf16x8 af[4], bfr[4];
#pragma unroll
      for (int a = 0; a < 4; ++a) {
        int row = wr + a * 16 + l15;
        int g = kk * 4 + quad;
        af[a] = *(const bf16x8*)&As[row * 64 + ((g ^ (row & 7)) << 3)];
      }
#pragma unroll
      for (int b = 0; b < 4; ++b) {
        int row = wc + b * 16 + l15;
        int g = kk * 4 + quad;
        bfr[b] = *(const bf16x8*)&Bs[row * 64 + ((g ^ (row & 7)) << 3)];
      }
#pragma unroll
      for (int a = 0; a < 4; ++a)
#pragma unroll
        for (int b = 0; b < 4; ++b)
          acc[a][b] = __builtin_amdgcn_mfma_f32_16x16x32_bf16(af[a], bfr[b], acc[a][b], 0, 0, 0);
    }
  }

  const long Doff = bz * dBatch;
#pragma unroll
  for (int a = 0; a < 4; ++a) {
    const int rb = (int)i0 + wr + a * 16 + quad * 4;   // C/D: row = quad*4+reg
    float rsc[4];
    if (SCALE_MODE == 1) {
#pragma unroll
      for (int r = 0; r < 4; ++r)
        rsc[r] = 22.627416997969522f / fmaxf(sqrtf(ssv[rb + r]), 1e-12f);
    }
#pragma unroll
    for (int b = 0; b < 4; ++b) {
      const int cc = (int)j0 + wc + b * 16 + l15;      // C/D: col = lane&15
      float csc = 1.f;
      if (SCALE_MODE == 2)
        csc = 22.627416997969522f / fmaxf(sqrtf(ssv[cc]), 1e-12f);
#pragma unroll
      for (int r = 0; r < 4; ++r) {
        float val = acc[a][b][r] * scale;
        if (SCALE_MODE == 1) val *= rsc[r];
        if (SCALE_MODE == 2) val *= csc;
        if (BIAS_MODE == 1) val += bias[rb + r];
        if (BIAS_MODE == 2) val += bias[cc];
        const long off = Doff + (long)(rb + r) * ldd + cc;
        if (RESID) val += resid[off];
        stv(D + off, val);
      }
    }
  }
}

// ---------------------------------------------------------------------------
// Fused spatial flash attention. Per block: frame t = blockIdx.y, 64 Q-rows
// (blockIdx.x), 4 waves each owning 16 rows. Q-frags in regs (64 VGPR),
// O-accum [16 l][512 c] fp32 (128 VGPR). Loop over 32 K-tiles of 32 m:
//   stage K (global_load_lds, 1KB rows, src-side xor swizzle) + V (padded
//   LDS rows); S = QK^T via MFMA; P = exp(scale*S) unguarded (validated R4);
//   P -> wave-private LDS -> A-frag; O += P·V; l_run += rowsums.
// Epilogue: O/l_run -> oT[n][512] bf16.
// ---------------------------------------------------------------------------
__global__ __launch_bounds__(256, 2) void flash_spatial(
    const short* __restrict__ QK, const short* __restrict__ vB,
    short* __restrict__ oT, float scale) {
  __shared__ short Ks[32 * 512];       // 32 KB: 32 m-rows x 512 k (chunk-xor by m&7)
  __shared__ short Vs[512 * 40];       // 40 KB: 512 c-rows x 32 m, rows padded to 40
  __shared__ short Plds[4 * 16 * 40];  // 5 KB: per-wave P (16 l x 32 m, padded rows)
  const int tid = threadIdx.x;
  const int w = tid >> 6, lane = tid & 63;
  const int quad = lane >> 4, l15 = lane & 15;
  const long tb = (long)blockIdx.y * 1024;             // frame base n
  const long nbase = tb + blockIdx.x * 64;             // block's first Q row
  const int lw = w * 16;                               // wave's l offset

  // Q fragments: lane holds Q[l15][s*32 + quad*8 .. +8]
  bf16x8 qf[16];
  {
    const short* qrow = QK + (nbase + lw + l15) * 1024 + quad * 8;
#pragma unroll
    for (int s = 0; s < 16; ++s) qf[s] = *(const bf16x8*)(qrow + s * 32);
  }
  f32x4 oacc[32];
#pragma unroll
  for (int cb = 0; cb < 32; ++cb) oacc[cb] = (f32x4){0.f, 0.f, 0.f, 0.f};
  float lrun[4] = {0.f, 0.f, 0.f, 0.f};

  for (int tile = 0; tile < 32; ++tile) {
    const int m0 = tile * 32;
    __syncthreads();                                   // protect Ks/Vs reuse
    // K rows: wave w stages rows w*8..w*8+7, one full 1KB row per instr
#pragma unroll
    for (int i = 0; i < 8; ++i) {
      int m = w * 8 + i;
      ldscp16(QK + (tb + m0 + m) * 1024 + 512 + ((lane ^ (m & 7)) << 3),
              &Ks[m * 512 + lane * 8]);
    }
    // V tile: 512 c x 32 m -> padded rows (80 B: 2-way read conflicts = free)
#pragma unroll
    for (int it = 0; it < 8; ++it) {
      int idx = it * 256 + tid;
      int c = idx >> 2, ch = idx & 3;
      *(uint4*)&Vs[c * 40 + ch * 8] =
          *(const uint4*)(vB + (long)c * 16384 + tb + m0 + ch * 8);
    }
    __syncthreads();                                   // drains vmcnt -> tiles valid

    // S = Q K^T: two 16-m column blocks
    f32x4 sa0 = {}, sa1 = {};
#pragma unroll
    for (int s = 0; s < 16; ++s) {
      const int slot = ((s * 4 + quad) ^ (l15 & 7)) << 3;  // (row&7)==l15&7 for both mb
      bf16x8 b0 = *(const bf16x8*)&Ks[l15 * 512 + slot];
      bf16x8 b1 = *(const bf16x8*)&Ks[(16 + l15) * 512 + slot];
      sa0 = __builtin_amdgcn_mfma_f32_16x16x32_bf16(qf[s], b0, sa0, 0, 0, 0);
      sa1 = __builtin_amdgcn_mfma_f32_16x16x32_bf16(qf[s], b1, sa1, 0, 0, 0);
    }

    // P = exp(scale*S), row sums, store to wave-private LDS (no barrier)
#pragma unroll
    for (int r = 0; r < 4; ++r) {
      float p0 = __expf(sa0[r] * scale);
      float p1 = __expf(sa1[r] * scale);
      float rs = p0 + p1;
#pragma unroll
      for (int off = 1; off < 16; off <<= 1) rs += __shfl_xor(rs, off);
      lrun[r] += rs;
      Plds[(w * 16 + quad * 4 + r) * 40 + l15] = f2bf(p0);
      Plds[(w * 16 + quad * 4 + r) * 40 + 16 + l15] = f2bf(p1);
    }
    // A-frag for PV: P[l15][quad*8 .. +8] (same-wave write->read, lgkm-ordered)
    bf16x8 pa = *(const bf16x8*)&Plds[(w * 16 + l15) * 40 + quad * 8];
    // O += P V
#pragma unroll
    for (int cb = 0; cb < 32; ++cb) {
      bf16x8 vb = *(const bf16x8*)&Vs[(cb * 16 + l15) * 40 + quad * 8];
      oacc[cb] = __builtin_amdgcn_mfma_f32_16x16x32_bf16(pa, vb, oacc[cb], 0, 0, 0);
    }
  }

  float inv[4];
#pragma unroll
  for (int r = 0; r < 4; ++r) inv[r] = 1.f / lrun[r];
#pragma unroll
  for (int cb = 0; cb < 32; ++cb)
#pragma unroll
    for (int r = 0; r < 4; ++r)
      oT[(nbase + lw + quad * 4 + r) * 512 + cb * 16 + l15] =
          f2bf(oacc[cb][r] * inv[r]);
}

// ---------------------------------------------------------------------------
// Temporal attention v3 — block per pixel (1024 blocks, 4 waves, 34 KB LDS).
// ---------------------------------------------------------------------------
__global__ __launch_bounds__(256) void temporal_attn_v3(
    const short* __restrict__ qkv, const int* __restrict__ wndp,
    short* __restrict__ o, float scale) {
  constexpr int RS = 1032;                           // Q|K row: 1024 + 8 pad
  __shared__ short qk[16 * RS];
  __shared__ float Plds[16][17];
  const int tid = threadIdx.x;
  const int w = tid >> 6, lane = tid & 63;
  const int hw = blockIdx.x;
  const int wnd = *wndp;

#pragma unroll
  for (int i = 0; i < 8; ++i) {
    int ci = w * 8 + i;
    int t = ci >> 1, half = ci & 1;
    ldscp16(qkv + (long)(t * 1024 + hw) * 1536 + half * 512 + lane * 8,
            &qk[t * RS + half * 512 + lane * 8]);
  }
  const int c0 = lane * 8;
  uint4 vch[16];
#pragma unroll
  for (int tp = 0; tp < 16; ++tp)
    vch[tp] = *(const uint4*)(qkv + (long)(tp * 1024 + hw) * 1536 + 1024 + c0);
  __syncthreads();

  if (w == 0) {
    const int quad = lane >> 4, m = lane & 15;
    const short* rowp = &qk[m * RS + quad * 8];
    f32x4 sacc = {};
#pragma unroll
    for (int s = 0; s < 16; ++s) {
      bf16x8 aq = *(const bf16x8*)(rowp + s * 32);
      bf16x8 bk = *(const bf16x8*)(rowp + 512 + s * 32);
      sacc = __builtin_amdgcn_mfma_f32_16x16x32_bf16(aq, bk, sacc, 0, 0, 0);
    }
#pragma unroll
    for (int r = 0; r < 4; ++r) {
      const int i = quad * 4 + r;
      const int j = m;
      const bool allowed = (j <= i) && (wnd <= 0 || (i - j) < wnd);
      float val = allowed ? sacc[r] * scale : -1e30f;
      float mx = val;
#pragma unroll
      for (int off = 1; off < 16; off <<= 1) mx = fmaxf(mx, __shfl_xor(mx, off));
      float e = allowed ? __expf(val - mx) : 0.f;
      float sum = e;
#pragma unroll
      for (int off = 1; off < 16; off <<= 1) sum += __shfl_xor(sum, off);
      Plds[i][j] = e / sum;
    }
  }
  __syncthreads();

#pragma unroll
  for (int r = 0; r < 4; ++r) {
    const int t = w * 4 + r;
    const int tlo = (wnd > 0 && t - wnd + 1 > 0) ? t - wnd + 1 : 0;
    float a0 = 0.f, a1 = 0.f, a2 = 0.f, a3 = 0.f,
          a4 = 0.f, a5 = 0.f, a6 = 0.f, a7 = 0.f;
#pragma unroll
    for (int tp = 0; tp < 16; ++tp) {
      const float p = (tp >= tlo && tp <= t) ? Plds[t][tp] : 0.f;
      const uint4 vv = vch[tp];
      a0 += p * blo(vv.x); a1 += p * bhi(vv.x);
      a2 += p * blo(vv.y); a3 += p * bhi(vv.y);
      a4 += p * blo(vv.z); a5 += p * bhi(vv.z);
      a6 += p * blo(vv.w); a7 += p * bhi(vv.w);
    }
    uint4 ov;
    ov.x = packbf(a0, a1); ov.y = packbf(a2, a3);
    ov.z = packbf(a4, a5); ov.w = packbf(a6, a7);
    *(uint4*)(o + (long)(t * 1024 + hw) * 512 + c0) = ov;
  }
}

// ---------------------------------------------------------------------------
// Launch
// ---------------------------------------------------------------------------
extern "C" void kernel_launch(void* const* d_in, const int* in_sizes, int n_in,
                              void* d_out, int out_size, void* d_ws, size_t ws_size,
                              hipStream_t stream) {
  const float* x    = (const float*)d_in[0];
  const float* qs_w = (const float*)d_in[1];
  const float* qs_b = (const float*)d_in[2];
  const float* ks_w = (const float*)d_in[3];
  const float* ks_b = (const float*)d_in[4];
  const float* vs_w = (const float*)d_in[5];
  const float* vs_b = (const float*)d_in[6];
  const float* ps_w = (const float*)d_in[7];
  const float* ps_b = (const float*)d_in[8];
  const float* qt_w = (const float*)d_in[9];
  const float* qt_b = (const float*)d_in[10];
  const float* kt_w = (const float*)d_in[11];
  const float* kt_b = (const float*)d_in[12];
  const float* vt_w = (const float*)d_in[13];
  const float* vt_b = (const float*)d_in[14];
  const float* pt_w = (const float*)d_in[15];
  const float* pt_b = (const float*)d_in[16];
  const float* g_s  = (const float*)d_in[17];
  const float* g_t  = (const float*)d_in[18];
  const int*   wnd  = (const int*)d_in[19];
  float* out = (float*)d_out;

  // workspace carve (117 MB)
  char* w = (char*)d_ws;
  short* Wb   = (short*)(w);                             // 4 MB : 8 x [512][512] bf16
  float* Ball = (float*)(w + (4L << 20));                // 16 KB: biases
  float* ss_s = (float*)(w + (4L << 20) + (64 << 10));   // 64 KB: spatial sumsq
  float* ss_t = (float*)(w + (4L << 20) + (128 << 10));  // 64 KB: temporal sumsq
  short* hb   = (short*)(w + (5L << 20));                // 16 MB: [16384][512] x^T bf16
  short* QK   = (short*)(w + (21L << 20));               // 32/48 MB: q|k or q|k|v
  short* vB   = (short*)(w + (53L << 20));               // 16 MB: [512][16384] spatial V
  short* oT   = (short*)(w + (69L << 20));               // 16 MB: [16384][512] attn out
  (void)in_sizes; (void)n_in; (void)out_size; (void)ws_size;

  const float scale = 0.04419417382415922f;              // 512^-0.5

  zero_f<<<128, 256, 0, stream>>>(ss_s);                 // ss_s | ss_t
  cvt_w<<<8192, 256, 0, stream>>>(qs_w, ks_w, vs_w, ps_w, qt_w, kt_w, vt_w, pt_w,
                                  g_s, g_t, Wb);
  cvt_b<<<16, 256, 0, stream>>>(qs_b, ks_b, vs_b, ps_b, qt_b, kt_b, vt_b, pt_b, Ball);

  // ---------------- spatial ----------------
  txp_sumsq<<<dim3(256, 8, 1), 256, 0, stream>>>(x, hb, ss_s);
  // QK[n, 0:1024] = rms_n * (x^T . [Wq_g;Wk_g]^T)[n,o] + bias[o]
  gemm_nt<short, 2, 1, false><<<dim3(128, 8, 1), 256, 0, stream>>>(
      hb, Wb, QK, Ball, ss_s, nullptr, 512, 512, 512, 1024, 0, 0, 0, 1.f);
  // vB[c, n] = rms_n * (Wv_g . x^T)[c,n] + vs_b[c]
  gemm_nt<short, 1, 2, false><<<dim3(4, 128, 1), 256, 0, stream>>>(
      Wb + 2 * 262144, hb, vB, Ball + 1024, ss_s, nullptr,
      512, 512, 512, 16384, 0, 0, 0, 1.f);
  // fused S -> exp -> PV  (replaces S GEMM + softmax + PV GEMM)
  flash_spatial<<<dim3(16, 16, 1), 256, 0, stream>>>(QK, vB, oT, scale);
  // out[c,n] = x[c,n] + ps_b[c] + Wp[c,:] . oT[n,:]
  gemm_nt<float, 1, 0, true><<<dim3(4, 128, 1), 256, 0, stream>>>(
      Wb + 3 * 262144, oT, out, Ball + 1536, nullptr, x,
      512, 512, 512, 16384, 0, 0, 0, 1.f);

  // ---------------- temporal ----------------
  txp_sumsq<<<dim3(256, 8, 1), 256, 0, stream>>>(out, hb, ss_t);
  // QK[n, 0:1536] = rms_n * (x^T . [Wqt_g;Wkt_g;Wvt_g]^T)[n,o] + bias[o]
  gemm_nt<short, 2, 1, false><<<dim3(128, 12, 1), 256, 0, stream>>>(
      hb, Wb + 4 * 262144, QK, Ball + 2048, ss_t, nullptr,
      512, 512, 512, 1536, 0, 0, 0, 1.f);
  temporal_attn_v3<<<1024, 256, 0, stream>>>(QK, wnd, oT, scale);
  // out[c,n] += pt_b[c] + Wpt[c,:] . oT[n,:]
  gemm_nt<float, 1, 0, true><<<dim3(4, 128, 1), 256, 0, stream>>>(
      Wb + 7 * 262144, oT, out, Ball + 3584, nullptr, out,
      512, 512, 512, 16384, 0, 0, 0, 1.f);
}

// Round 6
// 331.528 us; speedup vs baseline: 1.4676x; 1.4676x over previous
//
#include <hip/hip_runtime.h>

// ---------------------------------------------------------------------------
// Types & helpers
// ---------------------------------------------------------------------------
typedef __attribute__((ext_vector_type(8))) short bf16x8;
typedef __attribute__((ext_vector_type(4))) float f32x4;

__device__ __forceinline__ short f2bf(float f) {
  union { float f; unsigned u; } a; a.f = f;
  unsigned r = a.u + 0x7fffu + ((a.u >> 16) & 1u);   // RNE
  return (short)(r >> 16);
}
__device__ __forceinline__ float bf2f(short s) {
  union { unsigned u; float f; } a;
  a.u = ((unsigned)(unsigned short)s) << 16; return a.f;
}
__device__ __forceinline__ float blo(unsigned u) { union { unsigned u; float f; } a; a.u = u << 16; return a.f; }
__device__ __forceinline__ float bhi(unsigned u) { union { unsigned u; float f; } a; a.u = u & 0xffff0000u; return a.f; }
__device__ __forceinline__ unsigned packbf(float lo, float hi) {
  return (unsigned)(unsigned short)f2bf(lo) | ((unsigned)(unsigned short)f2bf(hi) << 16);
}
__device__ __forceinline__ void ldscp16(const void* g, void* l) {
  __builtin_amdgcn_global_load_lds((const __attribute__((address_space(1))) void*)g,
                                   (__attribute__((address_space(3))) void*)l, 16, 0, 0);
}
__device__ __forceinline__ void stv(float* p, float v) { *p = v; }
__device__ __forceinline__ void stv(short* p, float v) { *p = f2bf(v); }

// ---------------------------------------------------------------------------
// Zero accumulators (ss_s | ss_t | rsum = 192 KB contiguous; ws is 0xAA)
// ---------------------------------------------------------------------------
__global__ __launch_bounds__(256) void zero_f(float* __restrict__ p) {
  p[blockIdx.x * 256 + threadIdx.x] = 0.f;
}

// ---------------------------------------------------------------------------
// Weight conversion to bf16. gamma folded into input-channel dim of q/k/v.
// Slots: 0 qs_g, 1 ks_g, 2 vs_g^T, 3 ps, 4 qt_g, 5 kt_g, 6 vt_g^T, 7 pt.
// Slots 2/6 stored TRANSPOSED [c_in][c_out] (for the W_pv = p·v fold GEMM).
// ---------------------------------------------------------------------------
__global__ __launch_bounds__(256) void cvt_w(
    const float* __restrict__ w0, const float* __restrict__ w1,
    const float* __restrict__ w2, const float* __restrict__ w3,
    const float* __restrict__ w4, const float* __restrict__ w5,
    const float* __restrict__ w6, const float* __restrict__ w7,
    const float* __restrict__ g_s, const float* __restrict__ g_t,
    short* __restrict__ out) {
  int idx = blockIdx.x * 256 + threadIdx.x;          // 8 * 262144
  const float* ws[8] = {w0, w1, w2, w3, w4, w5, w6, w7};
  int wi = idx >> 18, loc = idx & 262143;
  int r = loc >> 9, q = loc & 511;
  float v, g;
  if (wi == 2 || wi == 6) {                          // transposed, gamma by r=c_in
    v = ws[wi][q * 512 + r];
    g = (wi == 2) ? g_s[r] : g_t[r];
  } else {
    v = ws[wi][loc];
    g = (wi <= 1) ? g_s[q] : (wi == 4 || wi == 5) ? g_t[q] : 1.f;
  }
  out[idx] = f2bf(v * g);
}

__global__ __launch_bounds__(256) void cvt_b(
    const float* __restrict__ b0, const float* __restrict__ b1,
    const float* __restrict__ b2, const float* __restrict__ b3,
    const float* __restrict__ b4, const float* __restrict__ b5,
    const float* __restrict__ b6, const float* __restrict__ b7,
    float* __restrict__ out) {
  int idx = blockIdx.x * 256 + threadIdx.x;          // 8 * 512
  const float* bs[8] = {b0, b1, b2, b3, b4, b5, b6, b7};
  out[idx] = bs[idx >> 9][idx & 511];
}

// ---------------------------------------------------------------------------
// Folded bias: bt[o] = sum_c p_w[o][c]*v_b[c] + p_b[o] (softmax rows sum to 1,
// so the V bias commutes out of attention). blocks 0..511 spatial, 512..1023 t.
// ---------------------------------------------------------------------------
__global__ __launch_bounds__(64) void bias_fold(
    const float* __restrict__ ps_w, const float* __restrict__ vs_b,
    const float* __restrict__ ps_b, const float* __restrict__ pt_w,
    const float* __restrict__ vt_b, const float* __restrict__ pt_b,
    float* __restrict__ bt_s, float* __restrict__ bt_t) {
  const int b = blockIdx.x, lane = threadIdx.x;
  const bool sp = b < 512;
  const float* W = sp ? ps_w : pt_w;
  const float* vb = sp ? vs_b : vt_b;
  const float* pb = sp ? ps_b : pt_b;
  float* o = sp ? bt_s : bt_t;
  const int r = b & 511;
  float s = 0.f;
#pragma unroll
  for (int c = lane; c < 512; c += 64) s += W[r * 512 + c] * vb[c];
#pragma unroll
  for (int off = 32; off > 0; off >>= 1) s += __shfl_xor(s, off);
  if (lane == 0) o[r] = s + pb[r];
}

// ---------------------------------------------------------------------------
// Transpose + sum-of-squares. src: [512][16384] fp32 -> dst: [16384][512] bf16,
// ss[n] += sum_c src[c][n]^2. WXB: also write straight bf16 cast xb[c][n]
// (c-major, needed as the PV B-operand). RMS factor deferred to epilogues.
// ---------------------------------------------------------------------------
template <bool WXB>
__global__ __launch_bounds__(256) void txp_sumsq(
    const float* __restrict__ src, short* __restrict__ dst,
    short* __restrict__ xb, float* __restrict__ ss) {
  constexpr long N = 16384;
  __shared__ short T[64][66];
  __shared__ float part[16][16][4];
  const int tid = threadIdx.x;
  const long n0 = (long)blockIdx.x * 64;
  const int c0 = blockIdx.y * 64;
  const int n4 = (tid & 15) * 4;
  float s0 = 0.f, s1 = 0.f, s2 = 0.f, s3 = 0.f;
#pragma unroll
  for (int i = 0; i < 4; ++i) {
    int cl = i * 16 + (tid >> 4);
    float4 v = *(const float4*)&src[(long)(c0 + cl) * N + n0 + n4];
    s0 += v.x * v.x; s1 += v.y * v.y; s2 += v.z * v.z; s3 += v.w * v.w;
    short b0 = f2bf(v.x), b1 = f2bf(v.y), b2 = f2bf(v.z), b3 = f2bf(v.w);
    T[n4 + 0][cl] = b0; T[n4 + 1][cl] = b1;
    T[n4 + 2][cl] = b2; T[n4 + 3][cl] = b3;
    if (WXB) {
      uint2 o;
      o.x = (unsigned)(unsigned short)b0 | ((unsigned)(unsigned short)b1 << 16);
      o.y = (unsigned)(unsigned short)b2 | ((unsigned)(unsigned short)b3 << 16);
      *(uint2*)&xb[(long)(c0 + cl) * N + n0 + n4] = o;
    }
  }
  part[tid >> 4][tid & 15][0] = s0; part[tid >> 4][tid & 15][1] = s1;
  part[tid >> 4][tid & 15][2] = s2; part[tid >> 4][tid & 15][3] = s3;
  __syncthreads();
  if (tid < 64) {
    float s = 0.f;
#pragma unroll
    for (int cg = 0; cg < 16; ++cg) s += part[cg][tid >> 2][tid & 3];
    atomicAdd(&ss[n0 + tid], s);
  }
#pragma unroll
  for (int p = 0; p < 4; ++p) {
    int nl = p * 16 + (tid >> 4);
    int cl = (tid & 15) * 4;
    uint2 o;
    o.x = (unsigned)(unsigned short)T[nl][cl] |
          ((unsigned)(unsigned short)T[nl][cl + 1] << 16);
    o.y = (unsigned)(unsigned short)T[nl][cl + 2] |
          ((unsigned)(unsigned short)T[nl][cl + 3] << 16);
    *(uint2*)&dst[(n0 + nl) * 512 + c0 + cl] = o;
  }
}

// ---------------------------------------------------------------------------
// Generic NT GEMM: D[i,j] = f( scale * sum_k A[i,k]*B[j,k] ) (+bias,+resid)
// SCALE_MODE: 0 none; 1 row-rms sqrt(512)/sqrt(ss[bz*sB+i]);
//             2 col-rms (ss[bz*sB+j]); 3 row-recip 1/ss[bz*sB+i] (softmax den)
// EXP: store exp(scale*acc) (unguarded, validated R4: |S·scale| < ~2) and
//      atomicAdd UNSCALED row sums into rs[bz*sB+i]; col-rms applies after.
// BIAS_MODE: 0 none, 1 row bias[i], 2 col bias[j].
// 128x128 tile, BK=64, 4 waves, mfma_f32_16x16x32_bf16, xor-swizzled LDS.
// ---------------------------------------------------------------------------
template <typename OutT, int BIAS_MODE, int SCALE_MODE, bool RESID, bool EXP>
__global__ __launch_bounds__(256, 3) void gemm_nt(
    const short* __restrict__ A, const short* __restrict__ B,
    OutT* __restrict__ D, const float* __restrict__ bias,
    const float* __restrict__ ssv, float* __restrict__ rs,
    const float* __restrict__ resid,
    int K, int lda, int ldb, int ldd,
    long aBatch, long bBatch, long dBatch, long sBatch, float scale) {
  __shared__ short As[128 * 64];
  __shared__ short Bs[128 * 64];
  const int tid = threadIdx.x;
  const int bz = blockIdx.z;
  const long i0 = (long)blockIdx.x * 128;
  const long j0 = (long)blockIdx.y * 128;
  const short* Ab = A + bz * aBatch + i0 * lda;
  const short* Bb = B + bz * bBatch + j0 * ldb;
  const int srow = tid >> 3, scol = tid & 7;
  const int lane = tid & 63;
  const int wr = ((tid >> 7) & 1) * 64;
  const int wc = ((tid >> 6) & 1) * 64;
  const int quad = lane >> 4, l15 = lane & 15;

  f32x4 acc[4][4] = {};

  for (int k0 = 0; k0 < K; k0 += 64) {
    __syncthreads();
#pragma unroll
    for (int p = 0; p < 4; ++p) {
      int row = p * 32 + srow;
      int gc = (scol ^ (row & 7)) << 3;
      ldscp16(Ab + (long)row * lda + k0 + gc, &As[p * 2048 + tid * 8]);
    }
#pragma unroll
    for (int p = 0; p < 4; ++p) {
      int row = p * 32 + srow;
      int gc = (scol ^ (row & 7)) << 3;
      ldscp16(Bb + (long)row * ldb + k0 + gc, &Bs[p * 2048 + tid * 8]);
    }
    __syncthreads();
#pragma unroll
    for (int kk = 0; kk < 2; ++kk) {
      bf16x8 af[4], bfr[4];
#pragma unroll
      for (int a = 0; a < 4; ++a) {
        int row = wr + a * 16 + l15;
        int g = kk * 4 + quad;
        af[a] = *(const bf16x8*)&As[row * 64 + ((g ^ (row & 7)) << 3)];
      }
#pragma unroll
      for (int b = 0; b < 4; ++b) {
        int row = wc + b * 16 + l15;
        int g = kk * 4 + quad;
        bfr[b] = *(const bf16x8*)&Bs[row * 64 + ((g ^ (row & 7)) << 3)];
      }
#pragma unroll
      for (int a = 0; a < 4; ++a)
#pragma unroll
        for (int b = 0; b < 4; ++b)
          acc[a][b] = __builtin_amdgcn_mfma_f32_16x16x32_bf16(af[a], bfr[b], acc[a][b], 0, 0, 0);
    }
  }

  const long Doff = bz * dBatch;
#pragma unroll
  for (int a = 0; a < 4; ++a) {
    const int rb = (int)i0 + wr + a * 16 + quad * 4;   // C/D: row = quad*4+reg
    float rsc[4];
    if (SCALE_MODE == 1) {
#pragma unroll
      for (int r = 0; r < 4; ++r)
        rsc[r] = 22.627416997969522f /
                 fmaxf(sqrtf(ssv[bz * sBatch + rb + r]), 1e-12f);
    }
    if (SCALE_MODE == 3) {
#pragma unroll
      for (int r = 0; r < 4; ++r)
        rsc[r] = 1.f / ssv[bz * sBatch + rb + r];
    }
    float rowpart[4] = {0.f, 0.f, 0.f, 0.f};
#pragma unroll
    for (int b = 0; b < 4; ++b) {
      const int cc = (int)j0 + wc + b * 16 + l15;      // C/D: col = lane&15
      float csc = 1.f;
      if (SCALE_MODE == 2)
        csc = 22.627416997969522f /
              fmaxf(sqrtf(ssv[bz * sBatch + cc]), 1e-12f);
#pragma unroll
      for (int r = 0; r < 4; ++r) {
        float val = acc[a][b][r] * scale;
        if (EXP) { val = __expf(val); rowpart[r] += val; }
        if (SCALE_MODE == 1 || SCALE_MODE == 3) val *= rsc[r];
        if (SCALE_MODE == 2) val *= csc;
        if (BIAS_MODE == 1) val += bias[rb + r];
        if (BIAS_MODE == 2) val += bias[cc];
        const long off = Doff + (long)(rb + r) * ldd + cc;
        if (RESID) val += resid[off];
        stv(D + off, val);
      }
    }
    if (EXP) {
#pragma unroll
      for (int r = 0; r < 4; ++r) {
        float s = rowpart[r];
#pragma unroll
        for (int off = 1; off < 16; off <<= 1) s += __shfl_xor(s, off);
        if (l15 == 0) atomicAdd(&rs[bz * sBatch + rb + r], s);
      }
    }
  }
}

// ---------------------------------------------------------------------------
// Temporal attention v4 — block per pixel. qk: [16384][1024] (q|k rows),
// hb: [16384][512] raw bf16 x^T (V folded out: output is h~ = P·rms·hb,
// the final GEMM applies W_pv = pt_w·vt_w_g). ss: per-position sumsq.
// ---------------------------------------------------------------------------
__global__ __launch_bounds__(256) void temporal_attn_v4(
    const short* __restrict__ qk, const short* __restrict__ hb,
    const float* __restrict__ ss, const int* __restrict__ wndp,
    short* __restrict__ o, float scale) {
  constexpr int RS = 1032;                           // q|k row: 1024 + 8 pad
  __shared__ short qs[16 * RS];
  __shared__ float Plds[16][17];
  const int tid = threadIdx.x;
  const int w = tid >> 6, lane = tid & 63;
  const int hw = blockIdx.x;
  const int wnd = *wndp;

#pragma unroll
  for (int i = 0; i < 8; ++i) {
    int ci = w * 8 + i;
    int t = ci >> 1, half = ci & 1;
    ldscp16(qk + (long)(t * 1024 + hw) * 1024 + half * 512 + lane * 8,
            &qs[t * RS + half * 512 + lane * 8]);
  }
  const int c0 = lane * 8;
  uint4 vch[16];
#pragma unroll
  for (int tp = 0; tp < 16; ++tp)
    vch[tp] = *(const uint4*)(hb + (long)(tp * 1024 + hw) * 512 + c0);
  __syncthreads();

  if (w == 0) {
    const int quad = lane >> 4, m = lane & 15;
    const short* rowp = &qs[m * RS + quad * 8];
    f32x4 sacc = {};
#pragma unroll
    for (int s = 0; s < 16; ++s) {
      bf16x8 aq = *(const bf16x8*)(rowp + s * 32);
      bf16x8 bk = *(const bf16x8*)(rowp + 512 + s * 32);
      sacc = __builtin_amdgcn_mfma_f32_16x16x32_bf16(aq, bk, sacc, 0, 0, 0);
    }
    const float rmsm = 22.627416997969522f /
                       fmaxf(sqrtf(ss[m * 1024 + hw]), 1e-12f);
#pragma unroll
    for (int r = 0; r < 4; ++r) {
      const int i = quad * 4 + r;
      const int j = m;
      const bool allowed = (j <= i) && (wnd <= 0 || (i - j) < wnd);
      float val = allowed ? sacc[r] * scale : -1e30f;
      float mx = val;
#pragma unroll
      for (int off = 1; off < 16; off <<= 1) mx = fmaxf(mx, __shfl_xor(mx, off));
      float e = allowed ? __expf(val - mx) : 0.f;
      float sum = e;
#pragma unroll
      for (int off = 1; off < 16; off <<= 1) sum += __shfl_xor(sum, off);
      Plds[i][j] = (e / sum) * rmsm;                 // rms_m folded into P
    }
  }
  __syncthreads();

#pragma unroll
  for (int r = 0; r < 4; ++r) {
    const int t = w * 4 + r;
    const int tlo = (wnd > 0 && t - wnd + 1 > 0) ? t - wnd + 1 : 0;
    float a0 = 0.f, a1 = 0.f, a2 = 0.f, a3 = 0.f,
          a4 = 0.f, a5 = 0.f, a6 = 0.f, a7 = 0.f;
#pragma unroll
    for (int tp = 0; tp < 16; ++tp) {
      const float p = (tp >= tlo && tp <= t) ? Plds[t][tp] : 0.f;
      const uint4 vv = vch[tp];
      a0 += p * blo(vv.x); a1 += p * bhi(vv.x);
      a2 += p * blo(vv.y); a3 += p * bhi(vv.y);
      a4 += p * blo(vv.z); a5 += p * bhi(vv.z);
      a6 += p * blo(vv.w); a7 += p * bhi(vv.w);
    }
    uint4 ov;
    ov.x = packbf(a0, a1); ov.y = packbf(a2, a3);
    ov.z = packbf(a4, a5); ov.w = packbf(a6, a7);
    *(uint4*)(o + (long)(t * 1024 + hw) * 512 + c0) = ov;
  }
}

// ---------------------------------------------------------------------------
// Launch
// ---------------------------------------------------------------------------
extern "C" void kernel_launch(void* const* d_in, const int* in_sizes, int n_in,
                              void* d_out, int out_size, void* d_ws, size_t ws_size,
                              hipStream_t stream) {
  const float* x    = (const float*)d_in[0];
  const float* qs_w = (const float*)d_in[1];
  const float* qs_b = (const float*)d_in[2];
  const float* ks_w = (const float*)d_in[3];
  const float* ks_b = (const float*)d_in[4];
  const float* vs_w = (const float*)d_in[5];
  const float* vs_b = (const float*)d_in[6];
  const float* ps_w = (const float*)d_in[7];
  const float* ps_b = (const float*)d_in[8];
  const float* qt_w = (const float*)d_in[9];
  const float* qt_b = (const float*)d_in[10];
  const float* kt_w = (const float*)d_in[11];
  const float* kt_b = (const float*)d_in[12];
  const float* vt_w = (const float*)d_in[13];
  const float* vt_b = (const float*)d_in[14];
  const float* pt_w = (const float*)d_in[15];
  const float* pt_b = (const float*)d_in[16];
  const float* g_s  = (const float*)d_in[17];
  const float* g_t  = (const float*)d_in[18];
  const int*   wnd  = (const int*)d_in[19];
  float* out = (float*)d_out;

  // workspace carve (~118 MB of the ~268 MB ws)
  char* w = (char*)d_ws;
  short* Wb   = (short*)(w);                               // 4 MB: 8 weight slots
  float* Ball = (float*)(w + (4L << 20));                  // 16 KB biases
  float* ss_s = (float*)(w + (4L << 20) + (64 << 10));     // 64 KB
  float* ss_t = (float*)(w + (4L << 20) + (128 << 10));    // 64 KB
  float* rsum = (float*)(w + (4L << 20) + (192 << 10));    // 64 KB
  float* bt_s = (float*)(w + (4L << 20) + (256 << 10));    // 2 KB folded bias
  float* bt_t = (float*)(w + (4L << 20) + (260 << 10));    // 2 KB
  short* Wpv  = (short*)(w + (4L << 20) + (512 << 10));    // 1 MB: Wpv_s|Wpv_t
  short* hb   = (short*)(w + (6L << 20));                  // 16 MB: [16384][512]
  short* QK   = (short*)(w + (22L << 20));                 // 32 MB: [16384][1024]
  short* xb   = (short*)(w + (54L << 20));                 // 16 MB: [512][16384] bf16 x
  short* oT   = (short*)(w + (70L << 20));                 // 16 MB: [16384][512]
  short* S    = (short*)(w + (86L << 20));                 // 32 MB: [16][1024][1024]
  (void)in_sizes; (void)n_in; (void)out_size; (void)ws_size;

  const float scale = 0.04419417382415922f;                // 512^-0.5

  zero_f<<<192, 256, 0, stream>>>(ss_s);                   // ss_s | ss_t | rsum
  cvt_w<<<8192, 256, 0, stream>>>(qs_w, ks_w, vs_w, ps_w, qt_w, kt_w, vt_w, pt_w,
                                  g_s, g_t, Wb);
  cvt_b<<<16, 256, 0, stream>>>(qs_b, ks_b, vs_b, ps_b, qt_b, kt_b, vt_b, pt_b, Ball);
  bias_fold<<<1024, 64, 0, stream>>>(ps_w, vs_b, ps_b, pt_w, vt_b, pt_b, bt_s, bt_t);
  // Wpv[z] = p_w · v_w_g  (z=0 spatial slots 3·2, z=1 temporal slots 7·6)
  gemm_nt<short, 0, 0, false, false><<<dim3(4, 4, 2), 256, 0, stream>>>(
      Wb + 3 * 262144, Wb + 2 * 262144, Wpv, nullptr, nullptr, nullptr, nullptr,
      512, 512, 512, 512, 4 * 262144L, 4 * 262144L, 262144L, 0, 1.f);

  // ---------------- spatial ----------------
  txp_sumsq<true><<<dim3(256, 8, 1), 256, 0, stream>>>(x, hb, xb, ss_s);
  // QK[n,0:1024] = rms_n * (hb . [Wq_g;Wk_g]^T) + bias
  gemm_nt<short, 2, 1, false, false><<<dim3(128, 8, 1), 256, 0, stream>>>(
      hb, Wb, QK, Ball, ss_s, nullptr, nullptr, 512, 512, 512, 1024,
      0, 0, 0, 0, 1.f);
  // expS'[t][l][m] = exp(scale*q_l.k_m) * rms_m ; rsum += unscaled row sums
  gemm_nt<short, 0, 2, false, true><<<dim3(8, 8, 16), 256, 0, stream>>>(
      QK, QK + 512, S, nullptr, ss_s, rsum, nullptr, 512, 1024, 1024, 1024,
      1024L * 1024, 1024L * 1024, 1024L * 1024, 1024, scale);
  // h~[t*1024+l][c] = (1/rsum) * sum_m expS'[l,m] * xb[c,m]
  gemm_nt<short, 0, 3, false, false><<<dim3(8, 4, 16), 256, 0, stream>>>(
      S, xb, oT, nullptr, rsum, nullptr, nullptr, 1024, 1024, 16384, 512,
      1024L * 1024, 1024L, 1024L * 512, 1024, 1.f);
  // out[c,n] = x[c,n] + bt_s[c] + Wpv_s[c,:] . h~[n,:]
  gemm_nt<float, 1, 0, true, false><<<dim3(4, 128, 1), 256, 0, stream>>>(
      Wpv, oT, out, bt_s, nullptr, nullptr, x, 512, 512, 512, 16384,
      0, 0, 0, 0, 1.f);

  // ---------------- temporal ----------------
  txp_sumsq<false><<<dim3(256, 8, 1), 256, 0, stream>>>(out, hb, nullptr, ss_t);
  // QK[n,0:1024] = rms_n * (hb . [Wqt_g;Wkt_g]^T) + bias
  gemm_nt<short, 2, 1, false, false><<<dim3(128, 8, 1), 256, 0, stream>>>(
      hb, Wb + 4 * 262144, QK, Ball + 2048, ss_t, nullptr, nullptr,
      512, 512, 512, 1024, 0, 0, 0, 0, 1.f);
  temporal_attn_v4<<<1024, 256, 0, stream>>>(QK, hb, ss_t, wnd, oT, scale);
  // out[c,n] += bt_t[c] + Wpv_t[c,:] . h~[n,:]
  gemm_nt<float, 1, 0, true, false><<<dim3(4, 128, 1), 256, 0, stream>>>(
      Wpv + 262144, oT, out, bt_t, nullptr, nullptr, out, 512, 512, 512, 16384,
      0, 0, 0, 0, 1.f);
}

// Round 7
// 314.786 us; speedup vs baseline: 1.5456x; 1.0532x over previous
//
#include <hip/hip_runtime.h>

// ---------------------------------------------------------------------------
// Types & helpers
// ---------------------------------------------------------------------------
typedef __attribute__((ext_vector_type(8))) short bf16x8;
typedef __attribute__((ext_vector_type(4))) float f32x4;

__device__ __forceinline__ short f2bf(float f) {
  union { float f; unsigned u; } a; a.f = f;
  unsigned r = a.u + 0x7fffu + ((a.u >> 16) & 1u);   // RNE
  return (short)(r >> 16);
}
__device__ __forceinline__ float bf2f(short s) {
  union { unsigned u; float f; } a;
  a.u = ((unsigned)(unsigned short)s) << 16; return a.f;
}
__device__ __forceinline__ float blo(unsigned u) { union { unsigned u; float f; } a; a.u = u << 16; return a.f; }
__device__ __forceinline__ float bhi(unsigned u) { union { unsigned u; float f; } a; a.u = u & 0xffff0000u; return a.f; }
__device__ __forceinline__ unsigned packbf(float lo, float hi) {
  return (unsigned)(unsigned short)f2bf(lo) | ((unsigned)(unsigned short)f2bf(hi) << 16);
}
__device__ __forceinline__ void ldscp16(const void* g, void* l) {
  __builtin_amdgcn_global_load_lds((const __attribute__((address_space(1))) void*)g,
                                   (__attribute__((address_space(3))) void*)l, 16, 0, 0);
}
__device__ __forceinline__ void stv(float* p, float v) { *p = v; }
__device__ __forceinline__ void stv(short* p, float v) { *p = f2bf(v); }

// ---------------------------------------------------------------------------
// Merged setup: [0,8192) cvt_w  [8192,8384) zero 192KB  [8384,8400) cvt_b
// [8400,8656) bias_fold (wave per output row).
// cvt_w slots: 0 qs_g, 1 ks_g, 2 vs_g^T, 3 ps, 4 qt_g, 5 kt_g, 6 vt_g^T, 7 pt
// (slots 2/6 transposed [c_in][c_out] for the Wpv fold GEMM).
// bias_fold: bt[o] = sum_c p_w[o][c]*v_b[c] + p_b[o].
// ---------------------------------------------------------------------------
__global__ __launch_bounds__(256) void setup_all(
    const float* __restrict__ w0, const float* __restrict__ w1,
    const float* __restrict__ w2, const float* __restrict__ w3,
    const float* __restrict__ w4, const float* __restrict__ w5,
    const float* __restrict__ w6, const float* __restrict__ w7,
    const float* __restrict__ g_s, const float* __restrict__ g_t,
    short* __restrict__ Wb,
    const float* __restrict__ b0, const float* __restrict__ b1,
    const float* __restrict__ b2, const float* __restrict__ b3,
    const float* __restrict__ b4, const float* __restrict__ b5,
    const float* __restrict__ b6, const float* __restrict__ b7,
    float* __restrict__ Ball, float* __restrict__ zs,
    const float* __restrict__ ps_w, const float* __restrict__ vs_b,
    const float* __restrict__ ps_b, const float* __restrict__ pt_w,
    const float* __restrict__ vt_b, const float* __restrict__ pt_b,
    float* __restrict__ bt_s, float* __restrict__ bt_t) {
  const int bid = blockIdx.x, tid = threadIdx.x;
  if (bid < 8192) {                                  // ---- cvt_w ----
    int idx = bid * 256 + tid;
    const float* ws[8] = {w0, w1, w2, w3, w4, w5, w6, w7};
    int wi = idx >> 18, loc = idx & 262143;
    int r = loc >> 9, q = loc & 511;
    float v, g;
    if (wi == 2 || wi == 6) {                        // transposed, gamma on c_in
      v = ws[wi][q * 512 + r];
      g = (wi == 2) ? g_s[r] : g_t[r];
    } else {
      v = ws[wi][loc];
      g = (wi <= 1) ? g_s[q] : (wi == 4 || wi == 5) ? g_t[q] : 1.f;
    }
    Wb[idx] = f2bf(v * g);
  } else if (bid < 8384) {                           // ---- zero ss_s|ss_t|rsum
    zs[(bid - 8192) * 256 + tid] = 0.f;
  } else if (bid < 8400) {                           // ---- cvt_b ----
    int idx = (bid - 8384) * 256 + tid;
    const float* bs[8] = {b0, b1, b2, b3, b4, b5, b6, b7};
    Ball[idx] = bs[idx >> 9][idx & 511];
  } else {                                           // ---- bias_fold ----
    const int w = tid >> 6, lane = tid & 63;
    const int b = (bid - 8400) * 4 + w;              // [0,1024)
    const bool sp = b < 512;
    const float* W = sp ? ps_w : pt_w;
    const float* vb = sp ? vs_b : vt_b;
    const float* pb = sp ? ps_b : pt_b;
    float* o = sp ? bt_s : bt_t;
    const int r = b & 511;
    float s = 0.f;
#pragma unroll
    for (int c = lane; c < 512; c += 64) s += W[r * 512 + c] * vb[c];
#pragma unroll
    for (int off = 32; off > 0; off >>= 1) s += __shfl_xor(s, off);
    if (lane == 0) o[r] = s + pb[r];
  }
}

// ---------------------------------------------------------------------------
// Transpose + sum-of-squares (spatial stage only). src [512][16384] fp32 ->
// dst [16384][512] bf16 (x^T), xb [512][16384] bf16 (straight cast),
// ss[n] += sum_c src[c][n]^2.
// ---------------------------------------------------------------------------
__global__ __launch_bounds__(256) void txp_sumsq(
    const float* __restrict__ src, short* __restrict__ dst,
    short* __restrict__ xb, float* __restrict__ ss) {
  constexpr long N = 16384;
  __shared__ short T[64][66];
  __shared__ float part[16][16][4];
  const int tid = threadIdx.x;
  const long n0 = (long)blockIdx.x * 64;
  const int c0 = blockIdx.y * 64;
  const int n4 = (tid & 15) * 4;
  float s0 = 0.f, s1 = 0.f, s2 = 0.f, s3 = 0.f;
#pragma unroll
  for (int i = 0; i < 4; ++i) {
    int cl = i * 16 + (tid >> 4);
    float4 v = *(const float4*)&src[(long)(c0 + cl) * N + n0 + n4];
    s0 += v.x * v.x; s1 += v.y * v.y; s2 += v.z * v.z; s3 += v.w * v.w;
    short e0 = f2bf(v.x), e1 = f2bf(v.y), e2 = f2bf(v.z), e3 = f2bf(v.w);
    T[n4 + 0][cl] = e0; T[n4 + 1][cl] = e1;
    T[n4 + 2][cl] = e2; T[n4 + 3][cl] = e3;
    uint2 o;
    o.x = (unsigned)(unsigned short)e0 | ((unsigned)(unsigned short)e1 << 16);
    o.y = (unsigned)(unsigned short)e2 | ((unsigned)(unsigned short)e3 << 16);
    *(uint2*)&xb[(long)(c0 + cl) * N + n0 + n4] = o;
  }
  part[tid >> 4][tid & 15][0] = s0; part[tid >> 4][tid & 15][1] = s1;
  part[tid >> 4][tid & 15][2] = s2; part[tid >> 4][tid & 15][3] = s3;
  __syncthreads();
  if (tid < 64) {
    float s = 0.f;
#pragma unroll
    for (int cg = 0; cg < 16; ++cg) s += part[cg][tid >> 2][tid & 3];
    atomicAdd(&ss[n0 + tid], s);
  }
#pragma unroll
  for (int p = 0; p < 4; ++p) {
    int nl = p * 16 + (tid >> 4);
    int cl = (tid & 15) * 4;
    uint2 o;
    o.x = (unsigned)(unsigned short)T[nl][cl] |
          ((unsigned)(unsigned short)T[nl][cl + 1] << 16);
    o.y = (unsigned)(unsigned short)T[nl][cl + 2] |
          ((unsigned)(unsigned short)T[nl][cl + 3] << 16);
    *(uint2*)&dst[(n0 + nl) * 512 + c0 + cl] = o;
  }
}

// ---------------------------------------------------------------------------
// Generic NT GEMM: D[i,j] = f( scale * sum_k A[i,k]*B[j,k] ) (+bias,+resid)
// SCALE_MODE: 0 none; 1 row-rms sqrt(512)/sqrt(ss[bz*sB+i]);
//             2 col-rms (ss[bz*sB+j]); 3 row-recip 1/ss[bz*sB+i]
// RESID_MODE: 0 none; 1 fp32 same-layout; 2 bf16 same-layout;
//             3 bf16 transposed (residb[j*512 + i], uint2-gathered)
// EPI: 0 none; 1 EXP (store exp(scale*acc), atomicAdd row sums -> rs);
//      2 SUMSQ (atomicAdd row sum of val^2 -> rs, after bias/resid)
// 128x128 tile, BK=64, 4 waves, mfma_f32_16x16x32_bf16, xor-swizzled LDS.
// ---------------------------------------------------------------------------
template <typename OutT, int BIAS_MODE, int SCALE_MODE, int RESID_MODE, int EPI>
__global__ __launch_bounds__(256, 3) void gemm_nt(
    const short* __restrict__ A, const short* __restrict__ B,
    OutT* __restrict__ D, const float* __restrict__ bias,
    const float* __restrict__ ssv, float* __restrict__ rs,
    const float* __restrict__ residf, const short* __restrict__ residb,
    int K, int lda, int ldb, int ldd,
    long aBatch, long bBatch, long dBatch, long sBatch, float scale) {
  __shared__ short As[128 * 64];
  __shared__ short Bs[128 * 64];
  const int tid = threadIdx.x;
  const int bz = blockIdx.z;
  const long i0 = (long)blockIdx.x * 128;
  const long j0 = (long)blockIdx.y * 128;
  const short* Ab = A + bz * aBatch + i0 * lda;
  const short* Bb = B + bz * bBatch + j0 * ldb;
  const int srow = tid >> 3, scol = tid & 7;
  const int lane = tid & 63;
  const int wr = ((tid >> 7) & 1) * 64;
  const int wc = ((tid >> 6) & 1) * 64;
  const int quad = lane >> 4, l15 = lane & 15;

  f32x4 acc[4][4] = {};

  for (int k0 = 0; k0 < K; k0 += 64) {
    __syncthreads();
#pragma unroll
    for (int p = 0; p < 4; ++p) {
      int row = p * 32 + srow;
      int gc = (scol ^ (row & 7)) << 3;
      ldscp16(Ab + (long)row * lda + k0 + gc, &As[p * 2048 + tid * 8]);
    }
#pragma unroll
    for (int p = 0; p < 4; ++p) {
      int row = p * 32 + srow;
      int gc = (scol ^ (row & 7)) << 3;
      ldscp16(Bb + (long)row * ldb + k0 + gc, &Bs[p * 2048 + tid * 8]);
    }
    __syncthreads();
#pragma unroll
    for (int kk = 0; kk < 2; ++kk) {
      bf16x8 af[4], bfr[4];
#pragma unroll
      for (int a = 0; a < 4; ++a) {
        int row = wr + a * 16 + l15;
        int g = kk * 4 + quad;
        af[a] = *(const bf16x8*)&As[row * 64 + ((g ^ (row & 7)) << 3)];
      }
#pragma unroll
      for (int b = 0; b < 4; ++b) {
        int row = wc + b * 16 + l15;
        int g = kk * 4 + quad;
        bfr[b] = *(const bf16x8*)&Bs[row * 64 + ((g ^ (row & 7)) << 3)];
      }
#pragma unroll
      for (int a = 0; a < 4; ++a)
#pragma unroll
        for (int b = 0; b < 4; ++b)
          acc[a][b] = __builtin_amdgcn_mfma_f32_16x16x32_bf16(af[a], bfr[b], acc[a][b], 0, 0, 0);
    }
  }

  const long Doff = bz * dBatch;
#pragma unroll
  for (int a = 0; a < 4; ++a) {
    const int rb = (int)i0 + wr + a * 16 + quad * 4;   // C/D: row = quad*4+reg
    float rsc[4];
    if (SCALE_MODE == 1) {
#pragma unroll
      for (int r = 0; r < 4; ++r)
        rsc[r] = 22.627416997969522f /
                 fmaxf(sqrtf(ssv[bz * sBatch + rb + r]), 1e-12f);
    }
    if (SCALE_MODE == 3) {
#pragma unroll
      for (int r = 0; r < 4; ++r)
        rsc[r] = 1.f / ssv[bz * sBatch + rb + r];
    }
    float rowpart[4] = {0.f, 0.f, 0.f, 0.f};
#pragma unroll
    for (int b = 0; b < 4; ++b) {
      const int cc = (int)j0 + wc + b * 16 + l15;      // C/D: col = lane&15
      float csc = 1.f;
      if (SCALE_MODE == 2)
        csc = 22.627416997969522f /
              fmaxf(sqrtf(ssv[bz * sBatch + cc]), 1e-12f);
      uint2 rtv;
      if (RESID_MODE == 3)
        rtv = *(const uint2*)&residb[(long)cc * 512 + rb];  // 4 shorts r=0..3
#pragma unroll
      for (int r = 0; r < 4; ++r) {
        float val = acc[a][b][r] * scale;
        if (EPI == 1) { val = __expf(val); rowpart[r] += val; }
        if (SCALE_MODE == 1 || SCALE_MODE == 3) val *= rsc[r];
        if (SCALE_MODE == 2) val *= csc;
        if (BIAS_MODE == 1) val += bias[rb + r];
        if (BIAS_MODE == 2) val += bias[cc];
        const long off = Doff + (long)(rb + r) * ldd + cc;
        if (RESID_MODE == 1) val += residf[off];
        if (RESID_MODE == 2) val += bf2f(residb[off]);
        if (RESID_MODE == 3) val += bf2f(((const short*)&rtv)[r]);
        stv(D + off, val);
        if (EPI == 2) rowpart[r] += val * val;
      }
    }
    if (EPI) {
#pragma unroll
      for (int r = 0; r < 4; ++r) {
        float s = rowpart[r];
#pragma unroll
        for (int off = 1; off < 16; off <<= 1) s += __shfl_xor(s, off);
        if (l15 == 0) atomicAdd(&rs[bz * sBatch + rb + r], s);
      }
    }
  }
}

// ---------------------------------------------------------------------------
// Temporal attention v4 — block per pixel. qk: [16384][1024] (q|k rows),
// h2: [16384][512] bf16 (spatial-stage result; V folded out), ss: sumsq.
// ---------------------------------------------------------------------------
__global__ __launch_bounds__(256) void temporal_attn_v4(
    const short* __restrict__ qk, const short* __restrict__ h2,
    const float* __restrict__ ss, const int* __restrict__ wndp,
    short* __restrict__ o, float scale) {
  constexpr int RS = 1032;                           // q|k row: 1024 + 8 pad
  __shared__ short qs[16 * RS];
  __shared__ float Plds[16][17];
  const int tid = threadIdx.x;
  const int w = tid >> 6, lane = tid & 63;
  const int hw = blockIdx.x;
  const int wnd = *wndp;

#pragma unroll
  for (int i = 0; i < 8; ++i) {
    int ci = w * 8 + i;
    int t = ci >> 1, half = ci & 1;
    ldscp16(qk + (long)(t * 1024 + hw) * 1024 + half * 512 + lane * 8,
            &qs[t * RS + half * 512 + lane * 8]);
  }
  const int c0 = lane * 8;
  uint4 vch[16];
#pragma unroll
  for (int tp = 0; tp < 16; ++tp)
    vch[tp] = *(const uint4*)(h2 + (long)(tp * 1024 + hw) * 512 + c0);
  __syncthreads();

  if (w == 0) {
    const int quad = lane >> 4, m = lane & 15;
    const short* rowp = &qs[m * RS + quad * 8];
    f32x4 sacc = {};
#pragma unroll
    for (int s = 0; s < 16; ++s) {
      bf16x8 aq = *(const bf16x8*)(rowp + s * 32);
      bf16x8 bk = *(const bf16x8*)(rowp + 512 + s * 32);
      sacc = __builtin_amdgcn_mfma_f32_16x16x32_bf16(aq, bk, sacc, 0, 0, 0);
    }
    const float rmsm = 22.627416997969522f /
                       fmaxf(sqrtf(ss[m * 1024 + hw]), 1e-12f);
#pragma unroll
    for (int r = 0; r < 4; ++r) {
      const int i = quad * 4 + r;
      const int j = m;
      const bool allowed = (j <= i) && (wnd <= 0 || (i - j) < wnd);
      float val = allowed ? sacc[r] * scale : -1e30f;
      float mx = val;
#pragma unroll
      for (int off = 1; off < 16; off <<= 1) mx = fmaxf(mx, __shfl_xor(mx, off));
      float e = allowed ? __expf(val - mx) : 0.f;
      float sum = e;
#pragma unroll
      for (int off = 1; off < 16; off <<= 1) sum += __shfl_xor(sum, off);
      Plds[i][j] = (e / sum) * rmsm;                 // rms_m folded into P
    }
  }
  __syncthreads();

#pragma unroll
  for (int r = 0; r < 4; ++r) {
    const int t = w * 4 + r;
    const int tlo = (wnd > 0 && t - wnd + 1 > 0) ? t - wnd + 1 : 0;
    float a0 = 0.f, a1 = 0.f, a2 = 0.f, a3 = 0.f,
          a4 = 0.f, a5 = 0.f, a6 = 0.f, a7 = 0.f;
#pragma unroll
    for (int tp = 0; tp < 16; ++tp) {
      const float p = (tp >= tlo && tp <= t) ? Plds[t][tp] : 0.f;
      const uint4 vv = vch[tp];
      a0 += p * blo(vv.x); a1 += p * bhi(vv.x);
      a2 += p * blo(vv.y); a3 += p * bhi(vv.y);
      a4 += p * blo(vv.z); a5 += p * bhi(vv.z);
      a6 += p * blo(vv.w); a7 += p * bhi(vv.w);
    }
    uint4 ov;
    ov.x = packbf(a0, a1); ov.y = packbf(a2, a3);
    ov.z = packbf(a4, a5); ov.w = packbf(a6, a7);
    *(uint4*)(o + (long)(t * 1024 + hw) * 512 + c0) = ov;
  }
}

// ---------------------------------------------------------------------------
// Launch
// ---------------------------------------------------------------------------
extern "C" void kernel_launch(void* const* d_in, const int* in_sizes, int n_in,
                              void* d_out, int out_size, void* d_ws, size_t ws_size,
                              hipStream_t stream) {
  const float* x    = (const float*)d_in[0];
  const float* qs_w = (const float*)d_in[1];
  const float* qs_b = (const float*)d_in[2];
  const float* ks_w = (const float*)d_in[3];
  const float* ks_b = (const float*)d_in[4];
  const float* vs_w = (const float*)d_in[5];
  const float* vs_b = (const float*)d_in[6];
  const float* ps_w = (const float*)d_in[7];
  const float* ps_b = (const float*)d_in[8];
  const float* qt_w = (const float*)d_in[9];
  const float* qt_b = (const float*)d_in[10];
  const float* kt_w = (const float*)d_in[11];
  const float* kt_b = (const float*)d_in[12];
  const float* vt_w = (const float*)d_in[13];
  const float* vt_b = (const float*)d_in[14];
  const float* pt_w = (const float*)d_in[15];
  const float* pt_b = (const float*)d_in[16];
  const float* g_s  = (const float*)d_in[17];
  const float* g_t  = (const float*)d_in[18];
  const int*   wnd  = (const int*)d_in[19];
  float* out = (float*)d_out;

  // workspace carve (~134 MB)
  char* w = (char*)d_ws;
  short* Wb   = (short*)(w);                               // 4 MB: 8 weight slots
  float* Ball = (float*)(w + (4L << 20));                  // 16 KB biases
  float* ss_s = (float*)(w + (4L << 20) + (64 << 10));     // 64 KB
  float* ss_t = (float*)(w + (4L << 20) + (128 << 10));    // 64 KB
  float* rsum = (float*)(w + (4L << 20) + (192 << 10));    // 64 KB
  float* bt_s = (float*)(w + (4L << 20) + (256 << 10));    // 2 KB folded bias
  float* bt_t = (float*)(w + (4L << 20) + (260 << 10));    // 2 KB
  short* Wpv  = (short*)(w + (4L << 20) + (512 << 10));    // 1 MB: Wpv_s|Wpv_t
  short* hb   = (short*)(w + (6L << 20));                  // 16 MB: [16384][512] bf16 x^T
  short* QK   = (short*)(w + (22L << 20));                 // 32 MB: [16384][1024]
  short* xb   = (short*)(w + (54L << 20));                 // 16 MB: [512][16384] bf16 x
  short* oT   = (short*)(w + (70L << 20));                 // 16 MB: [16384][512] h~
  short* h2   = (short*)(w + (86L << 20));                 // 16 MB: [16384][512] spatial result
  short* S    = (short*)(w + (102L << 20));                // 32 MB: [16][1024][1024]
  (void)in_sizes; (void)n_in; (void)out_size; (void)ws_size;

  const float scale = 0.04419417382415922f;                // 512^-0.5

  // setup: cvt_w + zero(ss_s|ss_t|rsum) + cvt_b + bias_fold in one dispatch
  setup_all<<<8656, 256, 0, stream>>>(
      qs_w, ks_w, vs_w, ps_w, qt_w, kt_w, vt_w, pt_w, g_s, g_t, Wb,
      qs_b, ks_b, vs_b, ps_b, qt_b, kt_b, vt_b, pt_b, Ball, ss_s,
      ps_w, vs_b, ps_b, pt_w, vt_b, pt_b, bt_s, bt_t);
  // Wpv[z] = p_w · v_w_g  (z=0 spatial slots 3·2, z=1 temporal slots 7·6)
  gemm_nt<short, 0, 0, 0, 0><<<dim3(4, 4, 2), 256, 0, stream>>>(
      Wb + 3 * 262144, Wb + 2 * 262144, Wpv, nullptr, nullptr, nullptr,
      nullptr, nullptr, 512, 512, 512, 512, 4 * 262144L, 4 * 262144L,
      262144L, 0, 1.f);

  // ---------------- spatial ----------------
  txp_sumsq<<<dim3(256, 8, 1), 256, 0, stream>>>(x, hb, xb, ss_s);
  // QK[n,0:1024] = rms_n * (hb . [Wq_g;Wk_g]^T) + bias
  gemm_nt<short, 2, 1, 0, 0><<<dim3(128, 8, 1), 256, 0, stream>>>(
      hb, Wb, QK, Ball, ss_s, nullptr, nullptr, nullptr,
      512, 512, 512, 1024, 0, 0, 0, 0, 1.f);
  // expS'[t][l][m] = exp(scale*q_l.k_m) * rms_m ; rsum += unscaled row sums
  gemm_nt<short, 0, 2, 0, 1><<<dim3(8, 8, 16), 256, 0, stream>>>(
      QK, QK + 512, S, nullptr, ss_s, rsum, nullptr, nullptr,
      512, 1024, 1024, 1024,
      1024L * 1024, 1024L * 1024, 1024L * 1024, 1024, scale);
  // h~[n][c] = (1/rsum) * sum_m expS'[l,m] * xb[c,m]
  gemm_nt<short, 0, 3, 0, 0><<<dim3(8, 4, 16), 256, 0, stream>>>(
      S, xb, oT, nullptr, rsum, nullptr, nullptr, nullptr,
      1024, 1024, 16384, 512,
      1024L * 1024, 1024L, 1024L * 512, 1024, 1.f);
  // h2[n][c] = bf16( x^T[n][c] + bt_s[c] + (oT . Wpv_s^T)[n][c] ); ss_t += val^2
  gemm_nt<short, 2, 0, 2, 2><<<dim3(128, 4, 1), 256, 0, stream>>>(
      oT, Wpv, h2, bt_s, nullptr, ss_t, nullptr, hb,
      512, 512, 512, 512, 0, 0, 0, 0, 1.f);

  // ---------------- temporal ----------------
  // QK[n,0:1024] = rms_n * (h2 . [Wqt_g;Wkt_g]^T) + bias
  gemm_nt<short, 2, 1, 0, 0><<<dim3(128, 8, 1), 256, 0, stream>>>(
      h2, Wb + 4 * 262144, QK, Ball + 2048, ss_t, nullptr, nullptr, nullptr,
      512, 512, 512, 1024, 0, 0, 0, 0, 1.f);
  temporal_attn_v4<<<1024, 256, 0, stream>>>(QK, h2, ss_t, wnd, oT, scale);
  // out[c,n] = h2[n][c] + bt_t[c] + Wpv_t[c,:] . h~[n,:]   (fp32, c-major)
  gemm_nt<float, 1, 0, 3, 0><<<dim3(4, 128, 1), 256, 0, stream>>>(
      Wpv + 262144, oT, out, bt_t, nullptr, nullptr, nullptr, h2,
      512, 512, 512, 16384, 0, 0, 0, 0, 1.f);
}

// Round 9
// 309.744 us; speedup vs baseline: 1.5708x; 1.0163x over previous
//
#include <hip/hip_runtime.h>

// ---------------------------------------------------------------------------
// Types & helpers
// ---------------------------------------------------------------------------
typedef __attribute__((ext_vector_type(8))) short bf16x8;
typedef __attribute__((ext_vector_type(4))) float f32x4;

__device__ __forceinline__ short f2bf(float f) {
  union { float f; unsigned u; } a; a.f = f;
  unsigned r = a.u + 0x7fffu + ((a.u >> 16) & 1u);   // RNE
  return (short)(r >> 16);
}
__device__ __forceinline__ float bf2f(short s) {
  union { unsigned u; float f; } a;
  a.u = ((unsigned)(unsigned short)s) << 16; return a.f;
}
__device__ __forceinline__ float blo(unsigned u) { union { unsigned u; float f; } a; a.u = u << 16; return a.f; }
__device__ __forceinline__ float bhi(unsigned u) { union { unsigned u; float f; } a; a.u = u & 0xffff0000u; return a.f; }
__device__ __forceinline__ unsigned packbf(float lo, float hi) {
  return (unsigned)(unsigned short)f2bf(lo) | ((unsigned)(unsigned short)f2bf(hi) << 16);
}
__device__ __forceinline__ void ldscp16(const void* g, void* l) {
  __builtin_amdgcn_global_load_lds((const __attribute__((address_space(1))) void*)g,
                                   (__attribute__((address_space(3))) void*)l, 16, 0, 0);
}
__device__ __forceinline__ void stv(float* p, float v) { *p = v; }
__device__ __forceinline__ void stv(short* p, float v) { *p = f2bf(v); }

// ---------------------------------------------------------------------------
// Merged setup. Blocks:
//  [0,8192)      cvt_w: slots 0 qs^T_g,1 ks^T_g,2 vs^T_g,3 ps,4 qt^T_g,
//                5 kt^T_g,6 vt^T_g,7 pt  (q/k/v transposed [c_in][c_out],
//                gamma folded on c_in; needed by the fold GEMMs)
//  [8192,8512)   zero 320 KB (ss_s|ss_t|rsum|us|ut)
//  [8512,9024)   row-folds, 4 waves/block, row b = (bid-8512)*4+wave:
//     b<512   : bt_s[b]   = ps_w[b,:]·vs_b + ps_b[b]
//     b<1024  : bt_t[...] = pt_w·vt_b + pt_b
//     b<1536  : wus[c]    = g_s[c] * sum_o ks_w[o][c]*qs_b[o]   (u-vector wt)
//     b<2048  : wut[c]    = g_t[c] * sum_o kt_w[o][c]*qt_b[o]
// ---------------------------------------------------------------------------
__global__ __launch_bounds__(256) void setup_all(
    const float* __restrict__ w0, const float* __restrict__ w1,
    const float* __restrict__ w2, const float* __restrict__ w3,
    const float* __restrict__ w4, const float* __restrict__ w5,
    const float* __restrict__ w6, const float* __restrict__ w7,
    const float* __restrict__ g_s, const float* __restrict__ g_t,
    short* __restrict__ Wb, float* __restrict__ zs,
    const float* __restrict__ qs_b, const float* __restrict__ vs_b,
    const float* __restrict__ ps_b, const float* __restrict__ qt_b,
    const float* __restrict__ vt_b, const float* __restrict__ pt_b,
    float* __restrict__ bt_s, float* __restrict__ bt_t,
    float* __restrict__ wus, float* __restrict__ wut) {
  const int bid = blockIdx.x, tid = threadIdx.x;
  if (bid < 8192) {                                  // ---- cvt_w ----
    int idx = bid * 256 + tid;
    const float* ws[8] = {w0, w1, w2, w3, w4, w5, w6, w7};
    int wi = idx >> 18, loc = idx & 262143;
    int r = loc >> 9, q = loc & 511;
    float v, g;
    if (wi == 3 || wi == 7) { v = ws[wi][loc]; g = 1.f; }
    else {                                           // transposed, gamma on c_in=r
      v = ws[wi][q * 512 + r];
      g = (wi <= 2) ? g_s[r] : g_t[r];
    }
    Wb[idx] = f2bf(v * g);
  } else if (bid < 8512) {                           // ---- zero 320 KB ----
    zs[(bid - 8192) * 256 + tid] = 0.f;
  } else {                                           // ---- row folds ----
    const int w = tid >> 6, lane = tid & 63;
    const int b = (bid - 8512) * 4 + w;              // [0,2048)
    float s = 0.f;
    if (b < 1024) {                                  // bt = p_w.v_b + p_b
      const bool sp = b < 512;
      const float* W = sp ? w3 : w7;                 // ps_w : pt_w
      const float* vb = sp ? vs_b : vt_b;
      const int r = b & 511;
#pragma unroll
      for (int c = lane; c < 512; c += 64) s += W[r * 512 + c] * vb[c];
#pragma unroll
      for (int off = 32; off > 0; off >>= 1) s += __shfl_xor(s, off);
      if (lane == 0) (sp ? bt_s : bt_t)[r] = s + (sp ? ps_b : pt_b)[r];
    } else {                                         // wu = g * K_w^T.q_b
      const bool sp = b < 1536;
      const float* W = sp ? w1 : w5;                 // ks_w : kt_w
      const float* qb = sp ? qs_b : qt_b;
      const int c = b & 511;
#pragma unroll
      for (int o = lane; o < 512; o += 64) s += W[o * 512 + c] * qb[o];
#pragma unroll
      for (int off = 32; off > 0; off >>= 1) s += __shfl_xor(s, off);
      if (lane == 0)
        (sp ? wus : wut)[c] = s * (sp ? g_s[c] : g_t[c]);
    }
  }
}

// ---------------------------------------------------------------------------
// Transpose + sum-of-squares + u-dot (spatial). src [512][16384] fp32 ->
// dst [16384][512] bf16 (x^T), xb [512][16384] bf16 (straight cast),
// ss[n] += sum_c src[c][n]^2 ; us[n] += sum_c wu[c]*src[c][n].
// ---------------------------------------------------------------------------
__global__ __launch_bounds__(256) void txp_sumsq(
    const float* __restrict__ src, short* __restrict__ dst,
    short* __restrict__ xb, float* __restrict__ ss,
    const float* __restrict__ wu, float* __restrict__ us) {
  constexpr long N = 16384;
  __shared__ short T[64][66];
  __shared__ float part[16][16][4];
  __shared__ float part2[16][16][4];
  const int tid = threadIdx.x;
  const long n0 = (long)blockIdx.x * 64;
  const int c0 = blockIdx.y * 64;
  const int n4 = (tid & 15) * 4;
  float s0 = 0.f, s1 = 0.f, s2 = 0.f, s3 = 0.f;
  float u0 = 0.f, u1 = 0.f, u2 = 0.f, u3 = 0.f;
#pragma unroll
  for (int i = 0; i < 4; ++i) {
    int cl = i * 16 + (tid >> 4);
    float4 v = *(const float4*)&src[(long)(c0 + cl) * N + n0 + n4];
    float wc = wu[c0 + cl];
    s0 += v.x * v.x; s1 += v.y * v.y; s2 += v.z * v.z; s3 += v.w * v.w;
    u0 += wc * v.x; u1 += wc * v.y; u2 += wc * v.z; u3 += wc * v.w;
    short e0 = f2bf(v.x), e1 = f2bf(v.y), e2 = f2bf(v.z), e3 = f2bf(v.w);
    T[n4 + 0][cl] = e0; T[n4 + 1][cl] = e1;
    T[n4 + 2][cl] = e2; T[n4 + 3][cl] = e3;
    uint2 o;
    o.x = (unsigned)(unsigned short)e0 | ((unsigned)(unsigned short)e1 << 16);
    o.y = (unsigned)(unsigned short)e2 | ((unsigned)(unsigned short)e3 << 16);
    *(uint2*)&xb[(long)(c0 + cl) * N + n0 + n4] = o;
  }
  part[tid >> 4][tid & 15][0] = s0; part[tid >> 4][tid & 15][1] = s1;
  part[tid >> 4][tid & 15][2] = s2; part[tid >> 4][tid & 15][3] = s3;
  part2[tid >> 4][tid & 15][0] = u0; part2[tid >> 4][tid & 15][1] = u1;
  part2[tid >> 4][tid & 15][2] = u2; part2[tid >> 4][tid & 15][3] = u3;
  __syncthreads();
  if (tid < 64) {
    float s = 0.f, u = 0.f;
#pragma unroll
    for (int cg = 0; cg < 16; ++cg) {
      s += part[cg][tid >> 2][tid & 3];
      u += part2[cg][tid >> 2][tid & 3];
    }
    atomicAdd(&ss[n0 + tid], s);
    atomicAdd(&us[n0 + tid], u);
  }
#pragma unroll
  for (int p = 0; p < 4; ++p) {
    int nl = p * 16 + (tid >> 4);
    int cl = (tid & 15) * 4;
    uint2 o;
    o.x = (unsigned)(unsigned short)T[nl][cl] |
          ((unsigned)(unsigned short)T[nl][cl + 1] << 16);
    o.y = (unsigned)(unsigned short)T[nl][cl + 2] |
          ((unsigned)(unsigned short)T[nl][cl + 3] << 16);
    *(uint2*)&dst[(n0 + nl) * 512 + c0 + cl] = o;
  }
}

// ---------------------------------------------------------------------------
// Generic NT GEMM: D[i,j] = f( scale * sum_k A[i,k]*B[j,k] ) (+bias,+resid)
// SCALE_MODE: 0 none; 1 row-rms; 2 col-rms; 3 row-recip (softmax denom);
//             4 QK-fold+EXP: val = exp(scale*csc*(rms_row*acc + uvec[col])),
//               rowsum(atomic->rs) of unscaled exp, store val*csc.
// RESID_MODE: 0 none; 1 fp32 same-layout; 2 bf16 same-layout;
//             3 bf16 transposed (residb[j*512+i], uint2-gathered)
// EPI: 0 none; 1 EXP-rowsum (with SCALE4); 3 SUMSQ->rs + dot(wvec)->rs2
// 128x128 tile, BK=64, 4 waves, mfma_f32_16x16x32_bf16, xor-swizzled LDS.
// ---------------------------------------------------------------------------
template <typename OutT, int BIAS_MODE, int SCALE_MODE, int RESID_MODE, int EPI>
__global__ __launch_bounds__(256, 3) void gemm_nt(
    const short* __restrict__ A, const short* __restrict__ B,
    OutT* __restrict__ D, const float* __restrict__ bias,
    const float* __restrict__ ssv, const float* __restrict__ uvec,
    float* __restrict__ rs, float* __restrict__ rs2,
    const float* __restrict__ wvec,
    const float* __restrict__ residf, const short* __restrict__ residb,
    int K, int lda, int ldb, int ldd,
    long aBatch, long bBatch, long dBatch, long sBatch, float scale) {
  __shared__ short As[128 * 64];
  __shared__ short Bs[128 * 64];
  const int tid = threadIdx.x;
  const int bz = blockIdx.z;
  const long i0 = (long)blockIdx.x * 128;
  const long j0 = (long)blockIdx.y * 128;
  const short* Ab = A + bz * aBatch + i0 * lda;
  const short* Bb = B + bz * bBatch + j0 * ldb;
  const int srow = tid >> 3, scol = tid & 7;
  const int lane = tid & 63;
  const int wr = ((tid >> 7) & 1) * 64;
  const int wc = ((tid >> 6) & 1) * 64;
  const int quad = lane >> 4, l15 = lane & 15;

  f32x4 acc[4][4] = {};

  for (int k0 = 0; k0 < K; k0 += 64) {
    __syncthreads();
#pragma unroll
    for (int p = 0; p < 4; ++p) {
      int row = p * 32 + srow;
      int gc = (scol ^ (row & 7)) << 3;
      ldscp16(Ab + (long)row * lda + k0 + gc, &As[p * 2048 + tid * 8]);
    }
#pragma unroll
    for (int p = 0; p < 4; ++p) {
      int row = p * 32 + srow;
      int gc = (scol ^ (row & 7)) << 3;
      ldscp16(Bb + (long)row * ldb + k0 + gc, &Bs[p * 2048 + tid * 8]);
    }
    __syncthreads();
#pragma unroll
    for (int kk = 0; kk < 2; ++kk) {
      bf16x8 af[4], bfr[4];
#pragma unroll
      for (int a = 0; a < 4; ++a) {
        int row = wr + a * 16 + l15;
        int g = kk * 4 + quad;
        af[a] = *(const bf16x8*)&As[row * 64 + ((g ^ (row & 7)) << 3)];
      }
#pragma unroll
      for (int b = 0; b < 4; ++b) {
        int row = wc + b * 16 + l15;
        int g = kk * 4 + quad;
        bfr[b] = *(const bf16x8*)&Bs[row * 64 + ((g ^ (row & 7)) << 3)];
      }
#pragma unroll
      for (int a = 0; a < 4; ++a)
#pragma unroll
        for (int b = 0; b < 4; ++b)
          acc[a][b] = __builtin_amdgcn_mfma_f32_16x16x32_bf16(af[a], bfr[b], acc[a][b], 0, 0, 0);
    }
  }

  const long Doff = bz * dBatch;
#pragma unroll
  for (int a = 0; a < 4; ++a) {
    const int rb = (int)i0 + wr + a * 16 + quad * 4;   // C/D: row = quad*4+reg
    float rsc[4];
    if (SCALE_MODE == 1 || SCALE_MODE == 4) {
#pragma unroll
      for (int r = 0; r < 4; ++r)
        rsc[r] = 22.627416997969522f /
                 fmaxf(sqrtf(ssv[bz * sBatch + rb + r]), 1e-12f);
    }
    if (SCALE_MODE == 3) {
#pragma unroll
      for (int r = 0; r < 4; ++r)
        rsc[r] = 1.f / ssv[bz * sBatch + rb + r];
    }
    float rp1[4] = {0.f, 0.f, 0.f, 0.f};
    float rp2[4] = {0.f, 0.f, 0.f, 0.f};
#pragma unroll
    for (int b = 0; b < 4; ++b) {
      const int cc = (int)j0 + wc + b * 16 + l15;      // C/D: col = lane&15
      float csc = 1.f, uu = 0.f, wv = 0.f;
      if (SCALE_MODE == 2 || SCALE_MODE == 4)
        csc = 22.627416997969522f /
              fmaxf(sqrtf(ssv[bz * sBatch + cc]), 1e-12f);
      if (SCALE_MODE == 4) uu = uvec[bz * sBatch + cc];
      if (EPI == 3) wv = wvec[cc];
      uint2 rtv;
      if (RESID_MODE == 3)
        rtv = *(const uint2*)&residb[(long)cc * 512 + rb];
#pragma unroll
      for (int r = 0; r < 4; ++r) {
        float val;
        if (SCALE_MODE == 4) {
          val = __expf(scale * csc * (rsc[r] * acc[a][b][r] + uu));
          rp1[r] += val;
          val *= csc;
        } else {
          val = acc[a][b][r] * scale;
          if (SCALE_MODE == 1 || SCALE_MODE == 3) val *= rsc[r];
          if (SCALE_MODE == 2) val *= csc;
        }
        if (BIAS_MODE == 1) val += bias[rb + r];
        if (BIAS_MODE == 2) val += bias[cc];
        const long off = Doff + (long)(rb + r) * ldd + cc;
        if (RESID_MODE == 1) val += residf[off];
        if (RESID_MODE == 2) val += bf2f(residb[off]);
        if (RESID_MODE == 3) val += bf2f(((const short*)&rtv)[r]);
        stv(D + off, val);
        if (EPI == 3) { rp1[r] += val * val; rp2[r] += val * wv; }
      }
    }
    if (EPI == 1 || EPI == 3) {
#pragma unroll
      for (int r = 0; r < 4; ++r) {
        float s = rp1[r];
#pragma unroll
        for (int off = 1; off < 16; off <<= 1) s += __shfl_xor(s, off);
        if (l15 == 0) atomicAdd(&rs[bz * sBatch + rb + r], s);
      }
      if (EPI == 3) {
#pragma unroll
        for (int r = 0; r < 4; ++r) {
          float s = rp2[r];
#pragma unroll
          for (int off = 1; off < 16; off <<= 1) s += __shfl_xor(s, off);
          if (l15 == 0) atomicAdd(&rs2[bz * sBatch + rb + r], s);
        }
      }
    }
  }
}

// ---------------------------------------------------------------------------
// Temporal attention v5 — QK-folded. h2: [16384][512] bf16, Tt = Mt.h2
// [16384][512] bf16. S[i,j] = scale*(rms_i*rms_j*(h2_i.Tt_j) + rms_j*ut_j).
// Block per pixel; V = rms-folded h2 (V projection folded into out-GEMM).
// ---------------------------------------------------------------------------
__global__ __launch_bounds__(256) void temporal_attn_v5(
    const short* __restrict__ h2, const short* __restrict__ Tt,
    const float* __restrict__ ss, const float* __restrict__ ut,
    const int* __restrict__ wndp, short* __restrict__ o, float scale) {
  constexpr int RS = 520;                            // 512 + 8 pad
  __shared__ short hq[16 * RS];
  __shared__ short tk[16 * RS];
  __shared__ float Plds[16][17];
  const int tid = threadIdx.x;
  const int w = tid >> 6, lane = tid & 63;
  const int hw = blockIdx.x;
  const int wnd = *wndp;

#pragma unroll
  for (int i = 0; i < 8; ++i) {
    int ci = w * 8 + i;                              // 32 rows: 0..15 h2, 16..31 Tt
    int t = ci & 15;
    const short* src = (ci < 16) ? h2 : Tt;
    short* dst = (ci < 16) ? hq : tk;
    ldscp16(src + (long)(t * 1024 + hw) * 512 + lane * 8,
            dst + t * RS + lane * 8);
  }
  const int c0 = lane * 8;
  uint4 vch[16];
#pragma unroll
  for (int tp = 0; tp < 16; ++tp)
    vch[tp] = *(const uint4*)(h2 + (long)(tp * 1024 + hw) * 512 + c0);
  __syncthreads();

  if (w == 0) {
    const int quad = lane >> 4, m = lane & 15;
    f32x4 sacc = {};
#pragma unroll
    for (int s = 0; s < 16; ++s) {
      bf16x8 aq = *(const bf16x8*)&hq[m * RS + quad * 8 + s * 32];
      bf16x8 bk = *(const bf16x8*)&tk[m * RS + quad * 8 + s * 32];
      sacc = __builtin_amdgcn_mfma_f32_16x16x32_bf16(aq, bk, sacc, 0, 0, 0);
    }
    const float rmsj = 22.627416997969522f /
                       fmaxf(sqrtf(ss[m * 1024 + hw]), 1e-12f);
    const float uj = ut[m * 1024 + hw];
#pragma unroll
    for (int r = 0; r < 4; ++r) {
      const int i = quad * 4 + r;
      const int j = m;
      const float rmsi = 22.627416997969522f /
                         fmaxf(sqrtf(ss[i * 1024 + hw]), 1e-12f);
      const bool allowed = (j <= i) && (wnd <= 0 || (i - j) < wnd);
      float val = allowed ? scale * (rmsi * rmsj * sacc[r] + rmsj * uj) : -1e30f;
      float mx = val;
#pragma unroll
      for (int off = 1; off < 16; off <<= 1) mx = fmaxf(mx, __shfl_xor(mx, off));
      float e = allowed ? __expf(val - mx) : 0.f;
      float sum = e;
#pragma unroll
      for (int off = 1; off < 16; off <<= 1) sum += __shfl_xor(sum, off);
      Plds[i][j] = (e / sum) * rmsj;                 // rms_j folded into P (V-fold)
    }
  }
  __syncthreads();

#pragma unroll
  for (int r = 0; r < 4; ++r) {
    const int t = w * 4 + r;
    const int tlo = (wnd > 0 && t - wnd + 1 > 0) ? t - wnd + 1 : 0;
    float a0 = 0.f, a1 = 0.f, a2 = 0.f, a3 = 0.f,
          a4 = 0.f, a5 = 0.f, a6 = 0.f, a7 = 0.f;
#pragma unroll
    for (int tp = 0; tp < 16; ++tp) {
      const float p = (tp >= tlo && tp <= t) ? Plds[t][tp] : 0.f;
      const uint4 vv = vch[tp];
      a0 += p * blo(vv.x); a1 += p * bhi(vv.x);
      a2 += p * blo(vv.y); a3 += p * bhi(vv.y);
      a4 += p * blo(vv.z); a5 += p * bhi(vv.z);
      a6 += p * blo(vv.w); a7 += p * bhi(vv.w);
    }
    uint4 ov;
    ov.x = packbf(a0, a1); ov.y = packbf(a2, a3);
    ov.z = packbf(a4, a5); ov.w = packbf(a6, a7);
    *(uint4*)(o + (long)(t * 1024 + hw) * 512 + c0) = ov;
  }
}

// ---------------------------------------------------------------------------
// Launch
// ---------------------------------------------------------------------------
extern "C" void kernel_launch(void* const* d_in, const int* in_sizes, int n_in,
                              void* d_out, int out_size, void* d_ws, size_t ws_size,
                              hipStream_t stream) {
  const float* x    = (const float*)d_in[0];
  const float* qs_w = (const float*)d_in[1];
  const float* qs_b = (const float*)d_in[2];
  const float* ks_w = (const float*)d_in[3];
  const float* ks_b = (const float*)d_in[4];
  const float* vs_w = (const float*)d_in[5];
  const float* vs_b = (const float*)d_in[6];
  const float* ps_w = (const float*)d_in[7];
  const float* ps_b = (const float*)d_in[8];
  const float* qt_w = (const float*)d_in[9];
  const float* qt_b = (const float*)d_in[10];
  const float* kt_w = (const float*)d_in[11];
  const float* kt_b = (const float*)d_in[12];
  const float* vt_w = (const float*)d_in[13];
  const float* vt_b = (const float*)d_in[14];
  const float* pt_w = (const float*)d_in[15];
  const float* pt_b = (const float*)d_in[16];
  const float* g_s  = (const float*)d_in[17];
  const float* g_t  = (const float*)d_in[18];
  const int*   wnd  = (const int*)d_in[19];
  float* out = (float*)d_out;
  (void)ks_b; (void)kt_b;   // K biases appear only via wu (zero cross-terms cancel)

  // workspace carve (~136 MB)
  char* w = (char*)d_ws;
  short* Wb   = (short*)(w);                               // 4 MB: 8 weight slots
  float* ss_s = (float*)(w + (4L << 20));                  // 64 KB (zeroed group start)
  float* ss_t = (float*)(w + (4L << 20) + (64 << 10));     // 64 KB
  float* rsum = (float*)(w + (4L << 20) + (128 << 10));    // 64 KB
  float* us   = (float*)(w + (4L << 20) + (192 << 10));    // 64 KB
  float* ut   = (float*)(w + (4L << 20) + (256 << 10));    // 64 KB (zeroed group end)
  float* bt_s = (float*)(w + (4L << 20) + (320 << 10));    // 2 KB folded bias
  float* bt_t = (float*)(w + (4L << 20) + (324 << 10));    // 2 KB
  float* wus  = (float*)(w + (4L << 20) + (328 << 10));    // 2 KB u-weights
  float* wut  = (float*)(w + (4L << 20) + (332 << 10));    // 2 KB
  short* Wpv  = (short*)(w + (4L << 20) + (512 << 10));    // 1 MB: Wpv_s|Wpv_t
  short* Mqk  = (short*)(w + (5L << 20) + (512 << 10));    // 1 MB: Mqk_s|Mqk_t
  short* hb   = (short*)(w + (8L << 20));                  // 16 MB: [16384][512] bf16 x^T
  short* Tb   = (short*)(w + (24L << 20));                 // 16 MB: [16384][512] T = M.h
  short* xb   = (short*)(w + (40L << 20));                 // 16 MB: [512][16384] bf16 x
  short* oT   = (short*)(w + (56L << 20));                 // 16 MB: [16384][512] h~
  short* h2   = (short*)(w + (72L << 20));                 // 16 MB: [16384][512]
  short* S    = (short*)(w + (88L << 20));                 // 32 MB: [16][1024][1024]
  (void)in_sizes; (void)n_in; (void)out_size; (void)ws_size;

  const float scale = 0.04419417382415922f;                // 512^-0.5

  setup_all<<<9024, 256, 0, stream>>>(
      qs_w, ks_w, vs_w, ps_w, qt_w, kt_w, vt_w, pt_w, g_s, g_t, Wb, ss_s,
      qs_b, vs_b, ps_b, qt_b, vt_b, pt_b, bt_s, bt_t, wus, wut);
  // Wpv[z] = p_w . v_w_g   (A slots 3,7 ; B slots 2,6)
  gemm_nt<short, 0, 0, 0, 0><<<dim3(4, 4, 2), 256, 0, stream>>>(
      Wb + 3 * 262144, Wb + 2 * 262144, Wpv, nullptr, nullptr, nullptr,
      nullptr, nullptr, nullptr, nullptr, nullptr,
      512, 512, 512, 512, 4 * 262144L, 4 * 262144L, 262144L, 0, 1.f);
  // Mqk[z] = Wq_g^T . Wk_g  (A slots 0,4 ; B slots 1,5)
  gemm_nt<short, 0, 0, 0, 0><<<dim3(4, 4, 2), 256, 0, stream>>>(
      Wb, Wb + 262144, Mqk, nullptr, nullptr, nullptr,
      nullptr, nullptr, nullptr, nullptr, nullptr,
      512, 512, 512, 512, 4 * 262144L, 4 * 262144L, 262144L, 0, 1.f);

  // ---------------- spatial ----------------
  txp_sumsq<<<dim3(256, 8, 1), 256, 0, stream>>>(x, hb, xb, ss_s, wus, us);
  // T[n][a] = hb[n,:] . Mqk_s[a,:]
  gemm_nt<short, 0, 0, 0, 0><<<dim3(128, 4, 1), 256, 0, stream>>>(
      hb, Mqk, Tb, nullptr, nullptr, nullptr, nullptr, nullptr, nullptr,
      nullptr, nullptr, 512, 512, 512, 512, 0, 0, 0, 0, 1.f);
  // expS'[t][l][m] = exp(scale*rms_m*(rms_l*(hb_l.T_m)+us_m))*rms_m ; rsum+=
  gemm_nt<short, 0, 4, 0, 1><<<dim3(8, 8, 16), 256, 0, stream>>>(
      hb, Tb, S, nullptr, ss_s, us, rsum, nullptr, nullptr, nullptr, nullptr,
      512, 512, 512, 1024,
      1024L * 512, 1024L * 512, 1024L * 1024, 1024, scale);
  // h~[n][c] = (1/rsum) * sum_m expS'[l,m] * xb[c,m]
  gemm_nt<short, 0, 3, 0, 0><<<dim3(8, 4, 16), 256, 0, stream>>>(
      S, xb, oT, nullptr, rsum, nullptr, nullptr, nullptr, nullptr,
      nullptr, nullptr, 1024, 1024, 16384, 512,
      1024L * 1024, 1024L, 1024L * 512, 1024, 1.f);
  // h2[n][c] = bf16( hb[n][c] + bt_s[c] + (oT.Wpv_s^T)[n][c] );
  //   ss_t += val^2 ; ut += val*wut[c]
  gemm_nt<short, 2, 0, 2, 3><<<dim3(128, 4, 1), 256, 0, stream>>>(
      oT, Wpv, h2, bt_s, nullptr, nullptr, ss_t, ut, wut, nullptr, hb,
      512, 512, 512, 512, 0, 0, 0, 1024, 1.f);

  // ---------------- temporal ----------------
  // Tt[n][a] = h2[n,:] . Mqk_t[a,:]
  gemm_nt<short, 0, 0, 0, 0><<<dim3(128, 4, 1), 256, 0, stream>>>(
      h2, Mqk + 262144, Tb, nullptr, nullptr, nullptr, nullptr, nullptr,
      nullptr, nullptr, nullptr, 512, 512, 512, 512, 0, 0, 0, 0, 1.f);
  temporal_attn_v5<<<1024, 256, 0, stream>>>(h2, Tb, ss_t, ut, wnd, oT, scale);
  // out[c,n] = h2[n][c] + bt_t[c] + Wpv_t[c,:] . h~[n,:]   (fp32, c-major)
  gemm_nt<float, 1, 0, 3, 0><<<dim3(4, 128, 1), 256, 0, stream>>>(
      Wpv + 262144, oT, out, bt_t, nullptr, nullptr, nullptr, nullptr,
      nullptr, nullptr, h2, 512, 512, 512, 16384, 0, 0, 0, 0, 1.f);
}

// Round 10
// 299.153 us; speedup vs baseline: 1.6264x; 1.0354x over previous
//
#include <hip/hip_runtime.h>

// ---------------------------------------------------------------------------
// Types & helpers
// ---------------------------------------------------------------------------
typedef __attribute__((ext_vector_type(8))) short bf16x8;
typedef __attribute__((ext_vector_type(4))) float f32x4;

__device__ __forceinline__ short f2bf(float f) {
  union { float f; unsigned u; } a; a.f = f;
  unsigned r = a.u + 0x7fffu + ((a.u >> 16) & 1u);   // RNE
  return (short)(r >> 16);
}
__device__ __forceinline__ float bf2f(short s) {
  union { unsigned u; float f; } a;
  a.u = ((unsigned)(unsigned short)s) << 16; return a.f;
}
__device__ __forceinline__ float blo(unsigned u) { union { unsigned u; float f; } a; a.u = u << 16; return a.f; }
__device__ __forceinline__ float bhi(unsigned u) { union { unsigned u; float f; } a; a.u = u & 0xffff0000u; return a.f; }
__device__ __forceinline__ unsigned packbf(float lo, float hi) {
  return (unsigned)(unsigned short)f2bf(lo) | ((unsigned)(unsigned short)f2bf(hi) << 16);
}
__device__ __forceinline__ void ldscp16(const void* g, void* l) {
  __builtin_amdgcn_global_load_lds((const __attribute__((address_space(1))) void*)g,
                                   (__attribute__((address_space(3))) void*)l, 16, 0, 0);
}
__device__ __forceinline__ void stv(float* p, float v) { *p = v; }
__device__ __forceinline__ void stv(short* p, float v) { *p = f2bf(v); }

// ---------------------------------------------------------------------------
// Merged setup. Blocks:
//  [0,8192)      cvt_w: slots 0 qs^T_g,1 ks^T_g,2 vs^T_g,3 ps,4 qt^T_g,
//                5 kt^T_g,6 vt^T_g,7 pt  (q/k/v transposed [c_in][c_out],
//                gamma folded on c_in; needed by the fold GEMMs)
//  [8192,8512)   zero 320 KB (ss_s|ss_t|rsum|us|ut)
//  [8512,9024)   row-folds, 4 waves/block, row b = (bid-8512)*4+wave:
//     b<512   : bt_s[b]   = ps_w[b,:].vs_b + ps_b[b]
//     b<1024  : bt_t[...] = pt_w.vt_b + pt_b
//     b<1536  : wus[c]    = g_s[c] * sum_o ks_w[o][c]*qs_b[o]   (u-vector wt)
//     b<2048  : wut[c]    = g_t[c] * sum_o kt_w[o][c]*qt_b[o]
// ---------------------------------------------------------------------------
__global__ __launch_bounds__(256) void setup_all(
    const float* __restrict__ w0, const float* __restrict__ w1,
    const float* __restrict__ w2, const float* __restrict__ w3,
    const float* __restrict__ w4, const float* __restrict__ w5,
    const float* __restrict__ w6, const float* __restrict__ w7,
    const float* __restrict__ g_s, const float* __restrict__ g_t,
    short* __restrict__ Wb, float* __restrict__ zs,
    const float* __restrict__ qs_b, const float* __restrict__ vs_b,
    const float* __restrict__ ps_b, const float* __restrict__ qt_b,
    const float* __restrict__ vt_b, const float* __restrict__ pt_b,
    float* __restrict__ bt_s, float* __restrict__ bt_t,
    float* __restrict__ wus, float* __restrict__ wut) {
  const int bid = blockIdx.x, tid = threadIdx.x;
  if (bid < 8192) {                                  // ---- cvt_w ----
    int idx = bid * 256 + tid;
    const float* ws[8] = {w0, w1, w2, w3, w4, w5, w6, w7};
    int wi = idx >> 18, loc = idx & 262143;
    int r = loc >> 9, q = loc & 511;
    float v, g;
    if (wi == 3 || wi == 7) { v = ws[wi][loc]; g = 1.f; }
    else {                                           // transposed, gamma on c_in=r
      v = ws[wi][q * 512 + r];
      g = (wi <= 2) ? g_s[r] : g_t[r];
    }
    Wb[idx] = f2bf(v * g);
  } else if (bid < 8512) {                           // ---- zero 320 KB ----
    zs[(bid - 8192) * 256 + tid] = 0.f;
  } else {                                           // ---- row folds ----
    const int w = tid >> 6, lane = tid & 63;
    const int b = (bid - 8512) * 4 + w;              // [0,2048)
    float s = 0.f;
    if (b < 1024) {                                  // bt = p_w.v_b + p_b
      const bool sp = b < 512;
      const float* W = sp ? w3 : w7;                 // ps_w : pt_w
      const float* vb = sp ? vs_b : vt_b;
      const int r = b & 511;
#pragma unroll
      for (int c = lane; c < 512; c += 64) s += W[r * 512 + c] * vb[c];
#pragma unroll
      for (int off = 32; off > 0; off >>= 1) s += __shfl_xor(s, off);
      if (lane == 0) (sp ? bt_s : bt_t)[r] = s + (sp ? ps_b : pt_b)[r];
    } else {                                         // wu = g * K_w^T.q_b
      const bool sp = b < 1536;
      const float* W = sp ? w1 : w5;                 // ks_w : kt_w
      const float* qb = sp ? qs_b : qt_b;
      const int c = b & 511;
#pragma unroll
      for (int o = lane; o < 512; o += 64) s += W[o * 512 + c] * qb[o];
#pragma unroll
      for (int off = 32; off > 0; off >>= 1) s += __shfl_xor(s, off);
      if (lane == 0)
        (sp ? wus : wut)[c] = s * (sp ? g_s[c] : g_t[c]);
    }
  }
}

// ---------------------------------------------------------------------------
// Transpose + sum-of-squares + u-dot (spatial). src [512][16384] fp32 ->
// dst [16384][512] bf16 (x^T), xb [512][16384] bf16 (straight cast),
// ss[n] += sum_c src[c][n]^2 ; us[n] += sum_c wu[c]*src[c][n].
// ---------------------------------------------------------------------------
__global__ __launch_bounds__(256) void txp_sumsq(
    const float* __restrict__ src, short* __restrict__ dst,
    short* __restrict__ xb, float* __restrict__ ss,
    const float* __restrict__ wu, float* __restrict__ us) {
  constexpr long N = 16384;
  __shared__ short T[64][66];
  __shared__ float part[16][16][4];
  __shared__ float part2[16][16][4];
  const int tid = threadIdx.x;
  const long n0 = (long)blockIdx.x * 64;
  const int c0 = blockIdx.y * 64;
  const int n4 = (tid & 15) * 4;
  float s0 = 0.f, s1 = 0.f, s2 = 0.f, s3 = 0.f;
  float u0 = 0.f, u1 = 0.f, u2 = 0.f, u3 = 0.f;
#pragma unroll
  for (int i = 0; i < 4; ++i) {
    int cl = i * 16 + (tid >> 4);
    float4 v = *(const float4*)&src[(long)(c0 + cl) * N + n0 + n4];
    float wc = wu[c0 + cl];
    s0 += v.x * v.x; s1 += v.y * v.y; s2 += v.z * v.z; s3 += v.w * v.w;
    u0 += wc * v.x; u1 += wc * v.y; u2 += wc * v.z; u3 += wc * v.w;
    short e0 = f2bf(v.x), e1 = f2bf(v.y), e2 = f2bf(v.z), e3 = f2bf(v.w);
    T[n4 + 0][cl] = e0; T[n4 + 1][cl] = e1;
    T[n4 + 2][cl] = e2; T[n4 + 3][cl] = e3;
    uint2 o;
    o.x = (unsigned)(unsigned short)e0 | ((unsigned)(unsigned short)e1 << 16);
    o.y = (unsigned)(unsigned short)e2 | ((unsigned)(unsigned short)e3 << 16);
    *(uint2*)&xb[(long)(c0 + cl) * N + n0 + n4] = o;
  }
  part[tid >> 4][tid & 15][0] = s0; part[tid >> 4][tid & 15][1] = s1;
  part[tid >> 4][tid & 15][2] = s2; part[tid >> 4][tid & 15][3] = s3;
  part2[tid >> 4][tid & 15][0] = u0; part2[tid >> 4][tid & 15][1] = u1;
  part2[tid >> 4][tid & 15][2] = u2; part2[tid >> 4][tid & 15][3] = u3;
  __syncthreads();
  if (tid < 64) {
    float s = 0.f, u = 0.f;
#pragma unroll
    for (int cg = 0; cg < 16; ++cg) {
      s += part[cg][tid >> 2][tid & 3];
      u += part2[cg][tid >> 2][tid & 3];
    }
    atomicAdd(&ss[n0 + tid], s);
    atomicAdd(&us[n0 + tid], u);
  }
#pragma unroll
  for (int p = 0; p < 4; ++p) {
    int nl = p * 16 + (tid >> 4);
    int cl = (tid & 15) * 4;
    uint2 o;
    o.x = (unsigned)(unsigned short)T[nl][cl] |
          ((unsigned)(unsigned short)T[nl][cl + 1] << 16);
    o.y = (unsigned)(unsigned short)T[nl][cl + 2] |
          ((unsigned)(unsigned short)T[nl][cl + 3] << 16);
    *(uint2*)&dst[(n0 + nl) * 512 + c0 + cl] = o;
  }
}

// ---------------------------------------------------------------------------
// Generic NT GEMM: D[i,j] = f( scale * sum_k A[i,k]*B[j,k] ) (+bias,+resid)
// SCALE_MODE: 0 none; 1 row-rms; 2 col-rms; 3 row-recip (softmax denom);
//             4 QK-fold+EXP: val = exp(scale*csc*(rms_row*acc + uvec[col])),
//               rowsum(atomic->rs) of unscaled exp, store val*csc.
// RESID_MODE: 0 none; 1 fp32 same-layout; 2 bf16 same-layout;
//             3 bf16 transposed (residb[j*512+i], uint2-gathered)
// EPI: 0 none; 1 EXP-rowsum (with SCALE4); 3 SUMSQ->rs + dot(wvec)->rs2
// BM: 128 (2x2 wave grid, 64x64/wave) or 256 (4x1 wave grid, 64x128/wave —
//     doubles MFMA-per-barrier, for the barrier-bound S-GEMM; VGPR headroom
//     measured: BM=128 compiles to 64 VGPRs).
// FOLD: z indexes slot tables A{3,7,0,4} B{2,6,1,5} in Wb (weight folds).
// BK=64, mfma_f32_16x16x32_bf16, xor-swizzled LDS.
// ---------------------------------------------------------------------------
template <typename OutT, int BIAS_MODE, int SCALE_MODE, int RESID_MODE, int EPI,
          int BM = 128, int FOLD = 0>
__global__ __launch_bounds__(256, BM == 128 ? 3 : 2) void gemm_nt(
    const short* __restrict__ A, const short* __restrict__ B,
    OutT* __restrict__ D, const float* __restrict__ bias,
    const float* __restrict__ ssv, const float* __restrict__ uvec,
    float* __restrict__ rs, float* __restrict__ rs2,
    const float* __restrict__ wvec,
    const float* __restrict__ residf, const short* __restrict__ residb,
    int K, int lda, int ldb, int ldd,
    long aBatch, long bBatch, long dBatch, long sBatch, float scale) {
  constexpr int WR = BM / 64;                        // wave rows
  constexpr int WC = 4 / WR;                         // wave cols
  constexpr int NW = (128 / WC) / 16;                // B-frags per wave (4 or 8)
  constexpr int AP = BM / 32;                        // A staging rounds
  __shared__ short As[BM * 64];
  __shared__ short Bs[128 * 64];
  const int tid = threadIdx.x;
  const int bz = blockIdx.z;
  const long i0 = (long)blockIdx.x * BM;
  const long j0 = (long)blockIdx.y * 128;
  long aOff, bOff;
  if (FOLD) {
    aOff = 262144L * (bz < 2 ? 3 + 4 * bz : 4 * (bz - 2));
    bOff = 262144L * (bz < 2 ? 2 + 4 * bz : 1 + 4 * (bz - 2));
  } else {
    aOff = bz * aBatch; bOff = bz * bBatch;
  }
  const short* Ab = A + aOff + i0 * lda;
  const short* Bb = B + bOff + j0 * ldb;
  const int srow = tid >> 3, scol = tid & 7;
  const int lane = tid & 63;
  const int waveid = tid >> 6;
  const int wr = (waveid / WC) * 64;
  const int wc = (waveid % WC) * 64;
  const int quad = lane >> 4, l15 = lane & 15;

  f32x4 acc[4][NW] = {};

  for (int k0 = 0; k0 < K; k0 += 64) {
    __syncthreads();
#pragma unroll
    for (int p = 0; p < AP; ++p) {
      int row = p * 32 + srow;
      int gc = (scol ^ (row & 7)) << 3;
      ldscp16(Ab + (long)row * lda + k0 + gc, &As[p * 2048 + tid * 8]);
    }
#pragma unroll
    for (int p = 0; p < 4; ++p) {
      int row = p * 32 + srow;
      int gc = (scol ^ (row & 7)) << 3;
      ldscp16(Bb + (long)row * ldb + k0 + gc, &Bs[p * 2048 + tid * 8]);
    }
    __syncthreads();
#pragma unroll
    for (int kk = 0; kk < 2; ++kk) {
      bf16x8 af[4], bfr[NW];
#pragma unroll
      for (int a = 0; a < 4; ++a) {
        int row = wr + a * 16 + l15;
        int g = kk * 4 + quad;
        af[a] = *(const bf16x8*)&As[row * 64 + ((g ^ (row & 7)) << 3)];
      }
#pragma unroll
      for (int b = 0; b < NW; ++b) {
        int row = wc + b * 16 + l15;
        int g = kk * 4 + quad;
        bfr[b] = *(const bf16x8*)&Bs[row * 64 + ((g ^ (row & 7)) << 3)];
      }
#pragma unroll
      for (int a = 0; a < 4; ++a)
#pragma unroll
        for (int b = 0; b < NW; ++b)
          acc[a][b] = __builtin_amdgcn_mfma_f32_16x16x32_bf16(af[a], bfr[b], acc[a][b], 0, 0, 0);
    }
  }

  const long Doff = bz * dBatch;
#pragma unroll
  for (int a = 0; a < 4; ++a) {
    const int rb = (int)i0 + wr + a * 16 + quad * 4;   // C/D: row = quad*4+reg
    float rsc[4];
    if (SCALE_MODE == 1 || SCALE_MODE == 4) {
#pragma unroll
      for (int r = 0; r < 4; ++r)
        rsc[r] = 22.627416997969522f /
                 fmaxf(sqrtf(ssv[bz * sBatch + rb + r]), 1e-12f);
    }
    if (SCALE_MODE == 3) {
#pragma unroll
      for (int r = 0; r < 4; ++r)
        rsc[r] = 1.f / ssv[bz * sBatch + rb + r];
    }
    float rp1[4] = {0.f, 0.f, 0.f, 0.f};
    float rp2[4] = {0.f, 0.f, 0.f, 0.f};
#pragma unroll
    for (int b = 0; b < NW; ++b) {
      const int cc = (int)j0 + wc + b * 16 + l15;      // C/D: col = lane&15
      float csc = 1.f, uu = 0.f, wv = 0.f;
      if (SCALE_MODE == 2 || SCALE_MODE == 4)
        csc = 22.627416997969522f /
              fmaxf(sqrtf(ssv[bz * sBatch + cc]), 1e-12f);
      if (SCALE_MODE == 4) uu = uvec[bz * sBatch + cc];
      if (EPI == 3) wv = wvec[cc];
      uint2 rtv;
      if (RESID_MODE == 3)
        rtv = *(const uint2*)&residb[(long)cc * 512 + rb];
#pragma unroll
      for (int r = 0; r < 4; ++r) {
        float val;
        if (SCALE_MODE == 4) {
          val = __expf(scale * csc * (rsc[r] * acc[a][b][r] + uu));
          rp1[r] += val;
          val *= csc;
        } else {
          val = acc[a][b][r] * scale;
          if (SCALE_MODE == 1 || SCALE_MODE == 3) val *= rsc[r];
          if (SCALE_MODE == 2) val *= csc;
        }
        if (BIAS_MODE == 1) val += bias[rb + r];
        if (BIAS_MODE == 2) val += bias[cc];
        const long off = Doff + (long)(rb + r) * ldd + cc;
        if (RESID_MODE == 1) val += residf[off];
        if (RESID_MODE == 2) val += bf2f(residb[off]);
        if (RESID_MODE == 3) val += bf2f(((const short*)&rtv)[r]);
        stv(D + off, val);
        if (EPI == 3) { rp1[r] += val * val; rp2[r] += val * wv; }
      }
    }
    if (EPI == 1 || EPI == 3) {
#pragma unroll
      for (int r = 0; r < 4; ++r) {
        float s = rp1[r];
#pragma unroll
        for (int off = 1; off < 16; off <<= 1) s += __shfl_xor(s, off);
        if (l15 == 0) atomicAdd(&rs[bz * sBatch + rb + r], s);
      }
      if (EPI == 3) {
#pragma unroll
        for (int r = 0; r < 4; ++r) {
          float s = rp2[r];
#pragma unroll
          for (int off = 1; off < 16; off <<= 1) s += __shfl_xor(s, off);
          if (l15 == 0) atomicAdd(&rs2[bz * sBatch + rb + r], s);
        }
      }
    }
  }
}

// ---------------------------------------------------------------------------
// Temporal attention v5 — QK-folded. h2: [16384][512] bf16, Tt = Mt.h2
// [16384][512] bf16. S[i,j] = scale*(rms_i*rms_j*(h2_i.Tt_j) + rms_j*ut_j).
// Block per pixel; V = rms-folded h2 (V projection folded into out-GEMM).
// ---------------------------------------------------------------------------
__global__ __launch_bounds__(256) void temporal_attn_v5(
    const short* __restrict__ h2, const short* __restrict__ Tt,
    const float* __restrict__ ss, const float* __restrict__ ut,
    const int* __restrict__ wndp, short* __restrict__ o, float scale) {
  constexpr int RS = 520;                            // 512 + 8 pad
  __shared__ short hq[16 * RS];
  __shared__ short tk[16 * RS];
  __shared__ float Plds[16][17];
  const int tid = threadIdx.x;
  const int w = tid >> 6, lane = tid & 63;
  const int hw = blockIdx.x;
  const int wnd = *wndp;

#pragma unroll
  for (int i = 0; i < 8; ++i) {
    int ci = w * 8 + i;                              // 32 rows: 0..15 h2, 16..31 Tt
    int t = ci & 15;
    const short* src = (ci < 16) ? h2 : Tt;
    short* dst = (ci < 16) ? hq : tk;
    ldscp16(src + (long)(t * 1024 + hw) * 512 + lane * 8,
            dst + t * RS + lane * 8);
  }
  const int c0 = lane * 8;
  uint4 vch[16];
#pragma unroll
  for (int tp = 0; tp < 16; ++tp)
    vch[tp] = *(const uint4*)(h2 + (long)(tp * 1024 + hw) * 512 + c0);
  __syncthreads();

  if (w == 0) {
    const int quad = lane >> 4, m = lane & 15;
    f32x4 sacc = {};
#pragma unroll
    for (int s = 0; s < 16; ++s) {
      bf16x8 aq = *(const bf16x8*)&hq[m * RS + quad * 8 + s * 32];
      bf16x8 bk = *(const bf16x8*)&tk[m * RS + quad * 8 + s * 32];
      sacc = __builtin_amdgcn_mfma_f32_16x16x32_bf16(aq, bk, sacc, 0, 0, 0);
    }
    const float rmsj = 22.627416997969522f /
                       fmaxf(sqrtf(ss[m * 1024 + hw]), 1e-12f);
    const float uj = ut[m * 1024 + hw];
#pragma unroll
    for (int r = 0; r < 4; ++r) {
      const int i = quad * 4 + r;
      const int j = m;
      const float rmsi = 22.627416997969522f /
                         fmaxf(sqrtf(ss[i * 1024 + hw]), 1e-12f);
      const bool allowed = (j <= i) && (wnd <= 0 || (i - j) < wnd);
      float val = allowed ? scale * (rmsi * rmsj * sacc[r] + rmsj * uj) : -1e30f;
      float mx = val;
#pragma unroll
      for (int off = 1; off < 16; off <<= 1) mx = fmaxf(mx, __shfl_xor(mx, off));
      float e = allowed ? __expf(val - mx) : 0.f;
      float sum = e;
#pragma unroll
      for (int off = 1; off < 16; off <<= 1) sum += __shfl_xor(sum, off);
      Plds[i][j] = (e / sum) * rmsj;                 // rms_j folded into P (V-fold)
    }
  }
  __syncthreads();

#pragma unroll
  for (int r = 0; r < 4; ++r) {
    const int t = w * 4 + r;
    const int tlo = (wnd > 0 && t - wnd + 1 > 0) ? t - wnd + 1 : 0;
    float a0 = 0.f, a1 = 0.f, a2 = 0.f, a3 = 0.f,
          a4 = 0.f, a5 = 0.f, a6 = 0.f, a7 = 0.f;
#pragma unroll
    for (int tp = 0; tp < 16; ++tp) {
      const float p = (tp >= tlo && tp <= t) ? Plds[t][tp] : 0.f;
      const uint4 vv = vch[tp];
      a0 += p * blo(vv.x); a1 += p * bhi(vv.x);
      a2 += p * blo(vv.y); a3 += p * bhi(vv.y);
      a4 += p * blo(vv.z); a5 += p * bhi(vv.z);
      a6 += p * blo(vv.w); a7 += p * bhi(vv.w);
    }
    uint4 ov;
    ov.x = packbf(a0, a1); ov.y = packbf(a2, a3);
    ov.z = packbf(a4, a5); ov.w = packbf(a6, a7);
    *(uint4*)(o + (long)(t * 1024 + hw) * 512 + c0) = ov;
  }
}

// ---------------------------------------------------------------------------
// Launch
// ---------------------------------------------------------------------------
extern "C" void kernel_launch(void* const* d_in, const int* in_sizes, int n_in,
                              void* d_out, int out_size, void* d_ws, size_t ws_size,
                              hipStream_t stream) {
  const float* x    = (const float*)d_in[0];
  const float* qs_w = (const float*)d_in[1];
  const float* qs_b = (const float*)d_in[2];
  const float* ks_w = (const float*)d_in[3];
  const float* ks_b = (const float*)d_in[4];
  const float* vs_w = (const float*)d_in[5];
  const float* vs_b = (const float*)d_in[6];
  const float* ps_w = (const float*)d_in[7];
  const float* ps_b = (const float*)d_in[8];
  const float* qt_w = (const float*)d_in[9];
  const float* qt_b = (const float*)d_in[10];
  const float* kt_w = (const float*)d_in[11];
  const float* kt_b = (const float*)d_in[12];
  const float* vt_w = (const float*)d_in[13];
  const float* vt_b = (const float*)d_in[14];
  const float* pt_w = (const float*)d_in[15];
  const float* pt_b = (const float*)d_in[16];
  const float* g_s  = (const float*)d_in[17];
  const float* g_t  = (const float*)d_in[18];
  const int*   wnd  = (const int*)d_in[19];
  float* out = (float*)d_out;
  (void)ks_b; (void)kt_b;   // K biases appear only via wu (zero cross-terms cancel)

  // workspace carve (~136 MB)
  char* w = (char*)d_ws;
  short* Wb   = (short*)(w);                               // 4 MB: 8 weight slots
  float* ss_s = (float*)(w + (4L << 20));                  // 64 KB (zeroed group start)
  float* ss_t = (float*)(w + (4L << 20) + (64 << 10));     // 64 KB
  float* rsum = (float*)(w + (4L << 20) + (128 << 10));    // 64 KB
  float* us   = (float*)(w + (4L << 20) + (192 << 10));    // 64 KB
  float* ut   = (float*)(w + (4L << 20) + (256 << 10));    // 64 KB (zeroed group end)
  float* bt_s = (float*)(w + (4L << 20) + (320 << 10));    // 2 KB folded bias
  float* bt_t = (float*)(w + (4L << 20) + (324 << 10));    // 2 KB
  float* wus  = (float*)(w + (4L << 20) + (328 << 10));    // 2 KB u-weights
  float* wut  = (float*)(w + (4L << 20) + (332 << 10));    // 2 KB
  short* WF   = (short*)(w + (4L << 20) + (512 << 10));    // 2 MB: Wpv_s|Wpv_t|Mqk_s|Mqk_t
  short* Wpv  = WF;
  short* Mqk  = WF + 2 * 262144;
  short* hb   = (short*)(w + (8L << 20));                  // 16 MB: [16384][512] bf16 x^T
  short* Tb   = (short*)(w + (24L << 20));                 // 16 MB: [16384][512] T = M.h
  short* xb   = (short*)(w + (40L << 20));                 // 16 MB: [512][16384] bf16 x
  short* oT   = (short*)(w + (56L << 20));                 // 16 MB: [16384][512] h~
  short* h2   = (short*)(w + (72L << 20));                 // 16 MB: [16384][512]
  short* S    = (short*)(w + (88L << 20));                 // 32 MB: [16][1024][1024]
  (void)in_sizes; (void)n_in; (void)out_size; (void)ws_size;

  const float scale = 0.04419417382415922f;                // 512^-0.5

  setup_all<<<9024, 256, 0, stream>>>(
      qs_w, ks_w, vs_w, ps_w, qt_w, kt_w, vt_w, pt_w, g_s, g_t, Wb, ss_s,
      qs_b, vs_b, ps_b, qt_b, vt_b, pt_b, bt_s, bt_t, wus, wut);
  // Merged weight folds (z slot tables): z0 Wpv_s=ps.vs_g, z1 Wpv_t=pt.vt_g,
  // z2 Mqk_s=qs_g^T.ks_g, z3 Mqk_t=qt_g^T.kt_g
  gemm_nt<short, 0, 0, 0, 0, 128, 1><<<dim3(4, 4, 4), 256, 0, stream>>>(
      Wb, Wb, WF, nullptr, nullptr, nullptr, nullptr, nullptr, nullptr,
      nullptr, nullptr, 512, 512, 512, 512, 0, 0, 262144L, 0, 1.f);

  // ---------------- spatial ----------------
  txp_sumsq<<<dim3(256, 8, 1), 256, 0, stream>>>(x, hb, xb, ss_s, wus, us);
  // T[n][a] = hb[n,:] . Mqk_s[a,:]
  gemm_nt<short, 0, 0, 0, 0><<<dim3(128, 4, 1), 256, 0, stream>>>(
      hb, Mqk, Tb, nullptr, nullptr, nullptr, nullptr, nullptr, nullptr,
      nullptr, nullptr, 512, 512, 512, 512, 0, 0, 0, 0, 1.f);
  // expS'[t][l][m] = exp(scale*rms_m*(rms_l*(hb_l.T_m)+us_m))*rms_m ; rsum+=
  // BIGTILE 256x128: barrier-bound at K=512 — double MFMA-per-barrier
  gemm_nt<short, 0, 4, 0, 1, 256><<<dim3(4, 8, 16), 256, 0, stream>>>(
      hb, Tb, S, nullptr, ss_s, us, rsum, nullptr, nullptr, nullptr, nullptr,
      512, 512, 512, 1024,
      1024L * 512, 1024L * 512, 1024L * 1024, 1024, scale);
  // h~[n][c] = (1/rsum) * sum_m expS'[l,m] * xb[c,m]
  gemm_nt<short, 0, 3, 0, 0><<<dim3(8, 4, 16), 256, 0, stream>>>(
      S, xb, oT, nullptr, rsum, nullptr, nullptr, nullptr, nullptr,
      nullptr, nullptr, 1024, 1024, 16384, 512,
      1024L * 1024, 1024L, 1024L * 512, 1024, 1.f);
  // h2[n][c] = bf16( hb[n][c] + bt_s[c] + (oT.Wpv_s^T)[n][c] );
  //   ss_t += val^2 ; ut += val*wut[c]
  gemm_nt<short, 2, 0, 2, 3><<<dim3(128, 4, 1), 256, 0, stream>>>(
      oT, Wpv, h2, bt_s, nullptr, nullptr, ss_t, ut, wut, nullptr, hb,
      512, 512, 512, 512, 0, 0, 0, 1024, 1.f);

  // ---------------- temporal ----------------
  // Tt[n][a] = h2[n,:] . Mqk_t[a,:]
  gemm_nt<short, 0, 0, 0, 0><<<dim3(128, 4, 1), 256, 0, stream>>>(
      h2, Mqk + 262144, Tb, nullptr, nullptr, nullptr, nullptr, nullptr,
      nullptr, nullptr, nullptr, 512, 512, 512, 512, 0, 0, 0, 0, 1.f);
  temporal_attn_v5<<<1024, 256, 0, stream>>>(h2, Tb, ss_t, ut, wnd, oT, scale);
  // out[c,n] = h2[n][c] + bt_t[c] + Wpv_t[c,:] . h~[n,:]   (fp32, c-major)
  gemm_nt<float, 1, 0, 3, 0><<<dim3(4, 128, 1), 256, 0, stream>>>(
      Wpv + 262144, oT, out, bt_t, nullptr, nullptr, nullptr, nullptr,
      nullptr, nullptr, h2, 512, 512, 512, 16384, 0, 0, 0, 0, 1.f);
}

// Round 11
// 294.932 us; speedup vs baseline: 1.6497x; 1.0143x over previous
//
#include <hip/hip_runtime.h>

// ---------------------------------------------------------------------------
// Types & helpers
// ---------------------------------------------------------------------------
typedef __attribute__((ext_vector_type(8))) short bf16x8;
typedef __attribute__((ext_vector_type(4))) float f32x4;

__device__ __forceinline__ short f2bf(float f) {
  union { float f; unsigned u; } a; a.f = f;
  unsigned r = a.u + 0x7fffu + ((a.u >> 16) & 1u);   // RNE
  return (short)(r >> 16);
}
__device__ __forceinline__ float bf2f(short s) {
  union { unsigned u; float f; } a;
  a.u = ((unsigned)(unsigned short)s) << 16; return a.f;
}
__device__ __forceinline__ float blo(unsigned u) { union { unsigned u; float f; } a; a.u = u << 16; return a.f; }
__device__ __forceinline__ float bhi(unsigned u) { union { unsigned u; float f; } a; a.u = u & 0xffff0000u; return a.f; }
__device__ __forceinline__ unsigned packbf(float lo, float hi) {
  return (unsigned)(unsigned short)f2bf(lo) | ((unsigned)(unsigned short)f2bf(hi) << 16);
}
__device__ __forceinline__ void ldscp16(const void* g, void* l) {
  __builtin_amdgcn_global_load_lds((const __attribute__((address_space(1))) void*)g,
                                   (__attribute__((address_space(3))) void*)l, 16, 0, 0);
}
__device__ __forceinline__ void stv(float* p, float v) { *p = v; }
__device__ __forceinline__ void stv(short* p, float v) { *p = f2bf(v); }

// ---------------------------------------------------------------------------
// Merged setup. Blocks:
//  [0,8192)      cvt_w: slots 0 qs^T_g,1 ks^T_g,2 vs^T_g,3 ps,4 qt^T_g,
//                5 kt^T_g,6 vt^T_g,7 pt  (q/k/v transposed [c_in][c_out],
//                gamma folded on c_in; needed by the fold GEMMs)
//  [8192,8512)   zero 320 KB (ss_s|ss_t|rsum|us|ut)
//  [8512,9024)   row-folds, 4 waves/block, row b = (bid-8512)*4+wave:
//     b<512   : bt_s[b]   = ps_w[b,:].vs_b + ps_b[b]
//     b<1024  : bt_t[...] = pt_w.vt_b + pt_b
//     b<1536  : wus[c]    = g_s[c] * sum_o ks_w[o][c]*qs_b[o]   (u-vector wt)
//     b<2048  : wut[c]    = g_t[c] * sum_o kt_w[o][c]*qt_b[o]
// ---------------------------------------------------------------------------
__global__ __launch_bounds__(256) void setup_all(
    const float* __restrict__ w0, const float* __restrict__ w1,
    const float* __restrict__ w2, const float* __restrict__ w3,
    const float* __restrict__ w4, const float* __restrict__ w5,
    const float* __restrict__ w6, const float* __restrict__ w7,
    const float* __restrict__ g_s, const float* __restrict__ g_t,
    short* __restrict__ Wb, float* __restrict__ zs,
    const float* __restrict__ qs_b, const float* __restrict__ vs_b,
    const float* __restrict__ ps_b, const float* __restrict__ qt_b,
    const float* __restrict__ vt_b, const float* __restrict__ pt_b,
    float* __restrict__ bt_s, float* __restrict__ bt_t,
    float* __restrict__ wus, float* __restrict__ wut) {
  const int bid = blockIdx.x, tid = threadIdx.x;
  if (bid < 8192) {                                  // ---- cvt_w ----
    int idx = bid * 256 + tid;
    const float* ws[8] = {w0, w1, w2, w3, w4, w5, w6, w7};
    int wi = idx >> 18, loc = idx & 262143;
    int r = loc >> 9, q = loc & 511;
    float v, g;
    if (wi == 3 || wi == 7) { v = ws[wi][loc]; g = 1.f; }
    else {                                           // transposed, gamma on c_in=r
      v = ws[wi][q * 512 + r];
      g = (wi <= 2) ? g_s[r] : g_t[r];
    }
    Wb[idx] = f2bf(v * g);
  } else if (bid < 8512) {                           // ---- zero 320 KB ----
    zs[(bid - 8192) * 256 + tid] = 0.f;
  } else {                                           // ---- row folds ----
    const int w = tid >> 6, lane = tid & 63;
    const int b = (bid - 8512) * 4 + w;              // [0,2048)
    float s = 0.f;
    if (b < 1024) {                                  // bt = p_w.v_b + p_b
      const bool sp = b < 512;
      const float* W = sp ? w3 : w7;                 // ps_w : pt_w
      const float* vb = sp ? vs_b : vt_b;
      const int r = b & 511;
#pragma unroll
      for (int c = lane; c < 512; c += 64) s += W[r * 512 + c] * vb[c];
#pragma unroll
      for (int off = 32; off > 0; off >>= 1) s += __shfl_xor(s, off);
      if (lane == 0) (sp ? bt_s : bt_t)[r] = s + (sp ? ps_b : pt_b)[r];
    } else {                                         // wu = g * K_w^T.q_b
      const bool sp = b < 1536;
      const float* W = sp ? w1 : w5;                 // ks_w : kt_w
      const float* qb = sp ? qs_b : qt_b;
      const int c = b & 511;
#pragma unroll
      for (int o = lane; o < 512; o += 64) s += W[o * 512 + c] * qb[o];
#pragma unroll
      for (int off = 32; off > 0; off >>= 1) s += __shfl_xor(s, off);
      if (lane == 0)
        (sp ? wus : wut)[c] = s * (sp ? g_s[c] : g_t[c]);
    }
  }
}

// ---------------------------------------------------------------------------
// Transpose + sum-of-squares + u-dot (spatial). src [512][16384] fp32 ->
// dst [16384][512] bf16 (x^T), xb [512][16384] bf16 (straight cast),
// ss[n] += sum_c src[c][n]^2 ; us[n] += sum_c wu[c]*src[c][n].
// ---------------------------------------------------------------------------
__global__ __launch_bounds__(256) void txp_sumsq(
    const float* __restrict__ src, short* __restrict__ dst,
    short* __restrict__ xb, float* __restrict__ ss,
    const float* __restrict__ wu, float* __restrict__ us) {
  constexpr long N = 16384;
  __shared__ short T[64][66];
  __shared__ float part[16][16][4];
  __shared__ float part2[16][16][4];
  const int tid = threadIdx.x;
  const long n0 = (long)blockIdx.x * 64;
  const int c0 = blockIdx.y * 64;
  const int n4 = (tid & 15) * 4;
  float s0 = 0.f, s1 = 0.f, s2 = 0.f, s3 = 0.f;
  float u0 = 0.f, u1 = 0.f, u2 = 0.f, u3 = 0.f;
#pragma unroll
  for (int i = 0; i < 4; ++i) {
    int cl = i * 16 + (tid >> 4);
    float4 v = *(const float4*)&src[(long)(c0 + cl) * N + n0 + n4];
    float wc = wu[c0 + cl];
    s0 += v.x * v.x; s1 += v.y * v.y; s2 += v.z * v.z; s3 += v.w * v.w;
    u0 += wc * v.x; u1 += wc * v.y; u2 += wc * v.z; u3 += wc * v.w;
    short e0 = f2bf(v.x), e1 = f2bf(v.y), e2 = f2bf(v.z), e3 = f2bf(v.w);
    T[n4 + 0][cl] = e0; T[n4 + 1][cl] = e1;
    T[n4 + 2][cl] = e2; T[n4 + 3][cl] = e3;
    uint2 o;
    o.x = (unsigned)(unsigned short)e0 | ((unsigned)(unsigned short)e1 << 16);
    o.y = (unsigned)(unsigned short)e2 | ((unsigned)(unsigned short)e3 << 16);
    *(uint2*)&xb[(long)(c0 + cl) * N + n0 + n4] = o;
  }
  part[tid >> 4][tid & 15][0] = s0; part[tid >> 4][tid & 15][1] = s1;
  part[tid >> 4][tid & 15][2] = s2; part[tid >> 4][tid & 15][3] = s3;
  part2[tid >> 4][tid & 15][0] = u0; part2[tid >> 4][tid & 15][1] = u1;
  part2[tid >> 4][tid & 15][2] = u2; part2[tid >> 4][tid & 15][3] = u3;
  __syncthreads();
  if (tid < 64) {
    float s = 0.f, u = 0.f;
#pragma unroll
    for (int cg = 0; cg < 16; ++cg) {
      s += part[cg][tid >> 2][tid & 3];
      u += part2[cg][tid >> 2][tid & 3];
    }
    atomicAdd(&ss[n0 + tid], s);
    atomicAdd(&us[n0 + tid], u);
  }
#pragma unroll
  for (int p = 0; p < 4; ++p) {
    int nl = p * 16 + (tid >> 4);
    int cl = (tid & 15) * 4;
    uint2 o;
    o.x = (unsigned)(unsigned short)T[nl][cl] |
          ((unsigned)(unsigned short)T[nl][cl + 1] << 16);
    o.y = (unsigned)(unsigned short)T[nl][cl + 2] |
          ((unsigned)(unsigned short)T[nl][cl + 3] << 16);
    *(uint2*)&dst[(n0 + nl) * 512 + c0 + cl] = o;
  }
}

// ---------------------------------------------------------------------------
// Generic NT GEMM: D[i,j] = f( scale * sum_k A[i,k]*B[j,k] ) (+bias,+resid)
// SCALE_MODE: 0 none; 1 row-rms; 2 col-rms; 3 row-recip (softmax denom);
//             4 QK-fold+EXP: val = exp(scale*csc*(rms_row*acc + uvec[col])),
//               rowsum(atomic->rs) of unscaled exp, store val*csc.
// RESID_MODE: 0 none; 1 fp32 same-layout; 2 bf16 same-layout;
//             3 bf16 transposed (residb[j*512+i], uint2-gathered)
// EPI: 0 none; 1 EXP-rowsum (with SCALE4); 3 SUMSQ->rs + dot(wvec)->rs2
// BM: 128 (2x2 wave grid) or 256 (4x1, doubles MFMA-per-barrier).
// BK: 64 or 128. BK=128 halves barrier count; LDS 64 KB -> 2 blocks/CU,
//     which matches the 512-block grids exactly (no occupancy loss — the
//     m132 trap only bites when a 3/CU grid drops to 2).
// FOLD: z indexes slot tables A{3,7,0,4} B{2,6,1,5} in Wb (weight folds).
// xor-swizzled LDS (chunk-xor by row & (BK/8-1)): 2-way max, free (m136).
// ---------------------------------------------------------------------------
template <typename OutT, int BIAS_MODE, int SCALE_MODE, int RESID_MODE, int EPI,
          int BM = 128, int FOLD = 0, int BK = 64>
__global__ __launch_bounds__(256, (BM == 128 && BK == 64) ? 3 : 2) void gemm_nt(
    const short* __restrict__ A, const short* __restrict__ B,
    OutT* __restrict__ D, const float* __restrict__ bias,
    const float* __restrict__ ssv, const float* __restrict__ uvec,
    float* __restrict__ rs, float* __restrict__ rs2,
    const float* __restrict__ wvec,
    const float* __restrict__ residf, const short* __restrict__ residb,
    int K, int lda, int ldb, int ldd,
    long aBatch, long bBatch, long dBatch, long sBatch, float scale) {
  constexpr int WR = BM / 64;                        // wave rows
  constexpr int WC = 4 / WR;                         // wave cols
  constexpr int NW = (128 / WC) / 16;                // B-frags per wave (4 or 8)
  constexpr int CH = BK / 8;                         // 16B chunks per row (8/16)
  constexpr int MSK = CH - 1;
  constexpr int RPR = 256 / CH;                      // rows staged per round
  __shared__ short As[BM * BK];
  __shared__ short Bs[128 * BK];
  const int tid = threadIdx.x;
  const int bz = blockIdx.z;
  const long i0 = (long)blockIdx.x * BM;
  const long j0 = (long)blockIdx.y * 128;
  long aOff, bOff;
  if (FOLD) {
    aOff = 262144L * (bz < 2 ? 3 + 4 * bz : 4 * (bz - 2));
    bOff = 262144L * (bz < 2 ? 2 + 4 * bz : 1 + 4 * (bz - 2));
  } else {
    aOff = bz * aBatch; bOff = bz * bBatch;
  }
  const short* Ab = A + aOff + i0 * lda;
  const short* Bb = B + bOff + j0 * ldb;
  const int srow = tid / CH, scol = tid & MSK;
  const int lane = tid & 63;
  const int waveid = tid >> 6;
  const int wr = (waveid / WC) * 64;
  const int wc = (waveid % WC) * 64;
  const int quad = lane >> 4, l15 = lane & 15;

  f32x4 acc[4][NW] = {};

  for (int k0 = 0; k0 < K; k0 += BK) {
    __syncthreads();
#pragma unroll
    for (int p = 0; p < BM / RPR; ++p) {
      int row = p * RPR + srow;
      int gc = (scol ^ (row & MSK)) << 3;
      ldscp16(Ab + (long)row * lda + k0 + gc, &As[p * 2048 + tid * 8]);
    }
#pragma unroll
    for (int p = 0; p < 128 / RPR; ++p) {
      int row = p * RPR + srow;
      int gc = (scol ^ (row & MSK)) << 3;
      ldscp16(Bb + (long)row * ldb + k0 + gc, &Bs[p * 2048 + tid * 8]);
    }
    __syncthreads();
#pragma unroll
    for (int kk = 0; kk < BK / 32; ++kk) {
      bf16x8 af[4], bfr[NW];
#pragma unroll
      for (int a = 0; a < 4; ++a) {
        int row = wr + a * 16 + l15;
        int g = kk * 4 + quad;
        af[a] = *(const bf16x8*)&As[row * BK + ((g ^ (row & MSK)) << 3)];
      }
#pragma unroll
      for (int b = 0; b < NW; ++b) {
        int row = wc + b * 16 + l15;
        int g = kk * 4 + quad;
        bfr[b] = *(const bf16x8*)&Bs[row * BK + ((g ^ (row & MSK)) << 3)];
      }
#pragma unroll
      for (int a = 0; a < 4; ++a)
#pragma unroll
        for (int b = 0; b < NW; ++b)
          acc[a][b] = __builtin_amdgcn_mfma_f32_16x16x32_bf16(af[a], bfr[b], acc[a][b], 0, 0, 0);
    }
  }

  const long Doff = bz * dBatch;
#pragma unroll
  for (int a = 0; a < 4; ++a) {
    const int rb = (int)i0 + wr + a * 16 + quad * 4;   // C/D: row = quad*4+reg
    float rsc[4];
    if (SCALE_MODE == 1 || SCALE_MODE == 4) {
#pragma unroll
      for (int r = 0; r < 4; ++r)
        rsc[r] = 22.627416997969522f /
                 fmaxf(sqrtf(ssv[bz * sBatch + rb + r]), 1e-12f);
    }
    if (SCALE_MODE == 3) {
#pragma unroll
      for (int r = 0; r < 4; ++r)
        rsc[r] = 1.f / ssv[bz * sBatch + rb + r];
    }
    float rp1[4] = {0.f, 0.f, 0.f, 0.f};
    float rp2[4] = {0.f, 0.f, 0.f, 0.f};
#pragma unroll
    for (int b = 0; b < NW; ++b) {
      const int cc = (int)j0 + wc + b * 16 + l15;      // C/D: col = lane&15
      float csc = 1.f, uu = 0.f, wv = 0.f;
      if (SCALE_MODE == 2 || SCALE_MODE == 4)
        csc = 22.627416997969522f /
              fmaxf(sqrtf(ssv[bz * sBatch + cc]), 1e-12f);
      if (SCALE_MODE == 4) uu = uvec[bz * sBatch + cc];
      if (EPI == 3) wv = wvec[cc];
      uint2 rtv;
      if (RESID_MODE == 3)
        rtv = *(const uint2*)&residb[(long)cc * 512 + rb];
#pragma unroll
      for (int r = 0; r < 4; ++r) {
        float val;
        if (SCALE_MODE == 4) {
          val = __expf(scale * csc * (rsc[r] * acc[a][b][r] + uu));
          rp1[r] += val;
          val *= csc;
        } else {
          val = acc[a][b][r] * scale;
          if (SCALE_MODE == 1 || SCALE_MODE == 3) val *= rsc[r];
          if (SCALE_MODE == 2) val *= csc;
        }
        if (BIAS_MODE == 1) val += bias[rb + r];
        if (BIAS_MODE == 2) val += bias[cc];
        const long off = Doff + (long)(rb + r) * ldd + cc;
        if (RESID_MODE == 1) val += residf[off];
        if (RESID_MODE == 2) val += bf2f(residb[off]);
        if (RESID_MODE == 3) val += bf2f(((const short*)&rtv)[r]);
        stv(D + off, val);
        if (EPI == 3) { rp1[r] += val * val; rp2[r] += val * wv; }
      }
    }
    if (EPI == 1 || EPI == 3) {
#pragma unroll
      for (int r = 0; r < 4; ++r) {
        float s = rp1[r];
#pragma unroll
        for (int off = 1; off < 16; off <<= 1) s += __shfl_xor(s, off);
        if (l15 == 0) atomicAdd(&rs[bz * sBatch + rb + r], s);
      }
      if (EPI == 3) {
#pragma unroll
        for (int r = 0; r < 4; ++r) {
          float s = rp2[r];
#pragma unroll
          for (int off = 1; off < 16; off <<= 1) s += __shfl_xor(s, off);
          if (l15 == 0) atomicAdd(&rs2[bz * sBatch + rb + r], s);
        }
      }
    }
  }
}

// ---------------------------------------------------------------------------
// Temporal attention v5 — QK-folded. h2: [16384][512] bf16, Tt = Mt.h2
// [16384][512] bf16. S[i,j] = scale*(rms_i*rms_j*(h2_i.Tt_j) + rms_j*ut_j).
// Block per pixel; V = rms-folded h2 (V projection folded into out-GEMM).
// ---------------------------------------------------------------------------
__global__ __launch_bounds__(256) void temporal_attn_v5(
    const short* __restrict__ h2, const short* __restrict__ Tt,
    const float* __restrict__ ss, const float* __restrict__ ut,
    const int* __restrict__ wndp, short* __restrict__ o, float scale) {
  constexpr int RS = 520;                            // 512 + 8 pad
  __shared__ short hq[16 * RS];
  __shared__ short tk[16 * RS];
  __shared__ float Plds[16][17];
  const int tid = threadIdx.x;
  const int w = tid >> 6, lane = tid & 63;
  const int hw = blockIdx.x;
  const int wnd = *wndp;

#pragma unroll
  for (int i = 0; i < 8; ++i) {
    int ci = w * 8 + i;                              // 32 rows: 0..15 h2, 16..31 Tt
    int t = ci & 15;
    const short* src = (ci < 16) ? h2 : Tt;
    short* dst = (ci < 16) ? hq : tk;
    ldscp16(src + (long)(t * 1024 + hw) * 512 + lane * 8,
            dst + t * RS + lane * 8);
  }
  const int c0 = lane * 8;
  uint4 vch[16];
#pragma unroll
  for (int tp = 0; tp < 16; ++tp)
    vch[tp] = *(const uint4*)(h2 + (long)(tp * 1024 + hw) * 512 + c0);
  __syncthreads();

  if (w == 0) {
    const int quad = lane >> 4, m = lane & 15;
    f32x4 sacc = {};
#pragma unroll
    for (int s = 0; s < 16; ++s) {
      bf16x8 aq = *(const bf16x8*)&hq[m * RS + quad * 8 + s * 32];
      bf16x8 bk = *(const bf16x8*)&tk[m * RS + quad * 8 + s * 32];
      sacc = __builtin_amdgcn_mfma_f32_16x16x32_bf16(aq, bk, sacc, 0, 0, 0);
    }
    const float rmsj = 22.627416997969522f /
                       fmaxf(sqrtf(ss[m * 1024 + hw]), 1e-12f);
    const float uj = ut[m * 1024 + hw];
#pragma unroll
    for (int r = 0; r < 4; ++r) {
      const int i = quad * 4 + r;
      const int j = m;
      const float rmsi = 22.627416997969522f /
                         fmaxf(sqrtf(ss[i * 1024 + hw]), 1e-12f);
      const bool allowed = (j <= i) && (wnd <= 0 || (i - j) < wnd);
      float val = allowed ? scale * (rmsi * rmsj * sacc[r] + rmsj * uj) : -1e30f;
      float mx = val;
#pragma unroll
      for (int off = 1; off < 16; off <<= 1) mx = fmaxf(mx, __shfl_xor(mx, off));
      float e = allowed ? __expf(val - mx) : 0.f;
      float sum = e;
#pragma unroll
      for (int off = 1; off < 16; off <<= 1) sum += __shfl_xor(sum, off);
      Plds[i][j] = (e / sum) * rmsj;                 // rms_j folded into P (V-fold)
    }
  }
  __syncthreads();

#pragma unroll
  for (int r = 0; r < 4; ++r) {
    const int t = w * 4 + r;
    const int tlo = (wnd > 0 && t - wnd + 1 > 0) ? t - wnd + 1 : 0;
    float a0 = 0.f, a1 = 0.f, a2 = 0.f, a3 = 0.f,
          a4 = 0.f, a5 = 0.f, a6 = 0.f, a7 = 0.f;
#pragma unroll
    for (int tp = 0; tp < 16; ++tp) {
      const float p = (tp >= tlo && tp <= t) ? Plds[t][tp] : 0.f;
      const uint4 vv = vch[tp];
      a0 += p * blo(vv.x); a1 += p * bhi(vv.x);
      a2 += p * blo(vv.y); a3 += p * bhi(vv.y);
      a4 += p * blo(vv.z); a5 += p * bhi(vv.z);
      a6 += p * blo(vv.w); a7 += p * bhi(vv.w);
    }
    uint4 ov;
    ov.x = packbf(a0, a1); ov.y = packbf(a2, a3);
    ov.z = packbf(a4, a5); ov.w = packbf(a6, a7);
    *(uint4*)(o + (long)(t * 1024 + hw) * 512 + c0) = ov;
  }
}

// ---------------------------------------------------------------------------
// Launch
// ---------------------------------------------------------------------------
extern "C" void kernel_launch(void* const* d_in, const int* in_sizes, int n_in,
                              void* d_out, int out_size, void* d_ws, size_t ws_size,
                              hipStream_t stream) {
  const float* x    = (const float*)d_in[0];
  const float* qs_w = (const float*)d_in[1];
  const float* qs_b = (const float*)d_in[2];
  const float* ks_w = (const float*)d_in[3];
  const float* ks_b = (const float*)d_in[4];
  const float* vs_w = (const float*)d_in[5];
  const float* vs_b = (const float*)d_in[6];
  const float* ps_w = (const float*)d_in[7];
  const float* ps_b = (const float*)d_in[8];
  const float* qt_w = (const float*)d_in[9];
  const float* qt_b = (const float*)d_in[10];
  const float* kt_w = (const float*)d_in[11];
  const float* kt_b = (const float*)d_in[12];
  const float* vt_w = (const float*)d_in[13];
  const float* vt_b = (const float*)d_in[14];
  const float* pt_w = (const float*)d_in[15];
  const float* pt_b = (const float*)d_in[16];
  const float* g_s  = (const float*)d_in[17];
  const float* g_t  = (const float*)d_in[18];
  const int*   wnd  = (const int*)d_in[19];
  float* out = (float*)d_out;
  (void)ks_b; (void)kt_b;   // K biases appear only via wu (zero cross-terms cancel)

  // workspace carve (~136 MB)
  char* w = (char*)d_ws;
  short* Wb   = (short*)(w);                               // 4 MB: 8 weight slots
  float* ss_s = (float*)(w + (4L << 20));                  // 64 KB (zeroed group start)
  float* ss_t = (float*)(w + (4L << 20) + (64 << 10));     // 64 KB
  float* rsum = (float*)(w + (4L << 20) + (128 << 10));    // 64 KB
  float* us   = (float*)(w + (4L << 20) + (192 << 10));    // 64 KB
  float* ut   = (float*)(w + (4L << 20) + (256 << 10));    // 64 KB (zeroed group end)
  float* bt_s = (float*)(w + (4L << 20) + (320 << 10));    // 2 KB folded bias
  float* bt_t = (float*)(w + (4L << 20) + (324 << 10));    // 2 KB
  float* wus  = (float*)(w + (4L << 20) + (328 << 10));    // 2 KB u-weights
  float* wut  = (float*)(w + (4L << 20) + (332 << 10));    // 2 KB
  short* WF   = (short*)(w + (4L << 20) + (512 << 10));    // 2 MB: Wpv_s|Wpv_t|Mqk_s|Mqk_t
  short* Wpv  = WF;
  short* Mqk  = WF + 2 * 262144;
  short* hb   = (short*)(w + (8L << 20));                  // 16 MB: [16384][512] bf16 x^T
  short* Tb   = (short*)(w + (24L << 20));                 // 16 MB: [16384][512] T = M.h
  short* xb   = (short*)(w + (40L << 20));                 // 16 MB: [512][16384] bf16 x
  short* oT   = (short*)(w + (56L << 20));                 // 16 MB: [16384][512] h~
  short* h2   = (short*)(w + (72L << 20));                 // 16 MB: [16384][512]
  short* S    = (short*)(w + (88L << 20));                 // 32 MB: [16][1024][1024]
  (void)in_sizes; (void)n_in; (void)out_size; (void)ws_size;

  const float scale = 0.04419417382415922f;                // 512^-0.5

  setup_all<<<9024, 256, 0, stream>>>(
      qs_w, ks_w, vs_w, ps_w, qt_w, kt_w, vt_w, pt_w, g_s, g_t, Wb, ss_s,
      qs_b, vs_b, ps_b, qt_b, vt_b, pt_b, bt_s, bt_t, wus, wut);
  // Merged weight folds (z slot tables): z0 Wpv_s=ps.vs_g, z1 Wpv_t=pt.vt_g,
  // z2 Mqk_s=qs_g^T.ks_g, z3 Mqk_t=qt_g^T.kt_g
  gemm_nt<short, 0, 0, 0, 0, 128, 1><<<dim3(4, 4, 4), 256, 0, stream>>>(
      Wb, Wb, WF, nullptr, nullptr, nullptr, nullptr, nullptr, nullptr,
      nullptr, nullptr, 512, 512, 512, 512, 0, 0, 262144L, 0, 1.f);

  // ---------------- spatial ----------------
  txp_sumsq<<<dim3(256, 8, 1), 256, 0, stream>>>(x, hb, xb, ss_s, wus, us);
  // T[n][a] = hb[n,:] . Mqk_s[a,:]   (BK=128: 4 barriers instead of 8)
  gemm_nt<short, 0, 0, 0, 0, 128, 0, 128><<<dim3(128, 4, 1), 256, 0, stream>>>(
      hb, Mqk, Tb, nullptr, nullptr, nullptr, nullptr, nullptr, nullptr,
      nullptr, nullptr, 512, 512, 512, 512, 0, 0, 0, 0, 1.f);
  // expS'[t][l][m] = exp(scale*rms_m*(rms_l*(hb_l.T_m)+us_m))*rms_m ; rsum+=
  // BIGTILE 256x128 (BK=64: 96KB would drop to 1 block/CU)
  gemm_nt<short, 0, 4, 0, 1, 256><<<dim3(4, 8, 16), 256, 0, stream>>>(
      hb, Tb, S, nullptr, ss_s, us, rsum, nullptr, nullptr, nullptr, nullptr,
      512, 512, 512, 1024,
      1024L * 512, 1024L * 512, 1024L * 1024, 1024, scale);
  // h~[n][c] = (1/rsum) * sum_m expS'[l,m] * xb[c,m]   (BK=128: 8 barriers)
  gemm_nt<short, 0, 3, 0, 0, 128, 0, 128><<<dim3(8, 4, 16), 256, 0, stream>>>(
      S, xb, oT, nullptr, rsum, nullptr, nullptr, nullptr, nullptr,
      nullptr, nullptr, 1024, 1024, 16384, 512,
      1024L * 1024, 1024L, 1024L * 512, 1024, 1.f);
  // h2[n][c] = bf16( hb[n][c] + bt_s[c] + (oT.Wpv_s^T)[n][c] );
  //   ss_t += val^2 ; ut += val*wut[c]
  gemm_nt<short, 2, 0, 2, 3, 128, 0, 128><<<dim3(128, 4, 1), 256, 0, stream>>>(
      oT, Wpv, h2, bt_s, nullptr, nullptr, ss_t, ut, wut, nullptr, hb,
      512, 512, 512, 512, 0, 0, 0, 1024, 1.f);

  // ---------------- temporal ----------------
  // Tt[n][a] = h2[n,:] . Mqk_t[a,:]
  gemm_nt<short, 0, 0, 0, 0, 128, 0, 128><<<dim3(128, 4, 1), 256, 0, stream>>>(
      h2, Mqk + 262144, Tb, nullptr, nullptr, nullptr, nullptr, nullptr,
      nullptr, nullptr, nullptr, 512, 512, 512, 512, 0, 0, 0, 0, 1.f);
  temporal_attn_v5<<<1024, 256, 0, stream>>>(h2, Tb, ss_t, ut, wnd, oT, scale);
  // out[c,n] = h2[n][c] + bt_t[c] + Wpv_t[c,:] . h~[n,:]   (fp32, c-major)
  gemm_nt<float, 1, 0, 3, 0, 128, 0, 128><<<dim3(4, 128, 1), 256, 0, stream>>>(
      Wpv + 262144, oT, out, bt_t, nullptr, nullptr, nullptr, nullptr,
      nullptr, nullptr, h2, 512, 512, 512, 16384, 0, 0, 0, 0, 1.f);
}